// Round 1
// baseline (172.329 us; speedup 1.0000x reference)
//
#include <hip/hip_runtime.h>
#include <cstddef>

typedef __attribute__((ext_vector_type(8))) short short8;
typedef __attribute__((ext_vector_type(4))) float f4;
typedef __attribute__((ext_vector_type(4))) unsigned int u4;

__device__ __forceinline__ unsigned int f2bf(float f){
  unsigned int u = __float_as_uint(f);
  u += 0x7fffu + ((u >> 16) & 1u);   // RNE to bf16
  return u >> 16;
}
__device__ __forceinline__ float fsign(float x){ return (x > 0.f) ? 1.f : ((x < 0.f) ? -1.f : 0.f); }
__device__ __forceinline__ float hclip(float x){ return fminf(1.f, fmaxf(-1.f, x)); }

// ---------------- prep: sign(W) fp32 -> bf16 {+1,-1,0} natural [N][K] ----------------
__global__ void prep_sign_k(const float* __restrict__ w, unsigned short* __restrict__ ws, int total){
  int i = (blockIdx.x * blockDim.x + threadIdx.x) * 8;
  if (i >= total) return;
  f4 a = *(const f4*)(w + i);
  f4 b = *(const f4*)(w + i + 4);
  unsigned short s[8];
  #pragma unroll
  for (int j = 0; j < 4; j++) s[j]   = (a[j] > 0.f) ? 0x3F80u : ((a[j] < 0.f) ? 0xBF80u : 0u);
  #pragma unroll
  for (int j = 0; j < 4; j++) s[4+j] = (b[j] > 0.f) ? 0x3F80u : ((b[j] < 0.f) ? 0xBF80u : 0u);
  u4 v;
  v.x = (unsigned)s[0] | ((unsigned)s[1] << 16);
  v.y = (unsigned)s[2] | ((unsigned)s[3] << 16);
  v.z = (unsigned)s[4] | ((unsigned)s[5] << 16);
  v.w = (unsigned)s[6] | ((unsigned)s[7] << 16);
  *(u4*)(ws + i) = v;
}

// ---------------- GEMM1: h1[16384,256] = x[16384,4096] @ signW1^T + sign(b1) ----------------
// BM=64, BN=256 (full), BK=64, 512 thr (8 waves, wave tile 32x64), dbuf LDS, XOR swizzle.
#define G1_ABUF 8192
#define G1_BBASE 16384
#define G1_BBUF 32768

__global__ __launch_bounds__(512) void gemm1_k(
    const float* __restrict__ x, const unsigned short* __restrict__ w1s,
    const float* __restrict__ b1, float* __restrict__ h1)
{
  __shared__ __align__(16) char lds[81920];
  const int tid  = threadIdx.x;
  const int lane = tid & 63;
  const int wid  = tid >> 6;
  const int wm   = wid >> 2, wn = wid & 3;
  const int row0 = blockIdx.x * 64;

  // A staging: thread -> row am, 8 contiguous k at ak0
  const int am  = tid >> 3;
  const int ak0 = (tid & 7) * 8;
  const float* xA = x + (size_t)(row0 + am) * 4096 + ak0;
  const int aoff  = ((am * 128) + (ak0 * 2)) ^ ((am & 7) << 4);

  // B staging: thread -> n row bn, 32 contiguous bf16 at bk0
  const int bn  = tid >> 1;
  const int bk0 = (tid & 1) * 32;
  const unsigned short* wB = w1s + bn * 4096 + bk0;
  const int bofs[4] = {
    (bn*128 + bk0*2 +  0) ^ ((bn & 7) << 4),
    (bn*128 + bk0*2 + 16) ^ ((bn & 7) << 4),
    (bn*128 + bk0*2 + 32) ^ ((bn & 7) << 4),
    (bn*128 + bk0*2 + 48) ^ ((bn & 7) << 4) };

  f4 acc[2][4];
  const f4 z = {0.f, 0.f, 0.f, 0.f};
  #pragma unroll
  for (int i = 0; i < 2; i++)
    #pragma unroll
    for (int j = 0; j < 4; j++) acc[i][j] = z;

  f4 ra0, ra1; u4 rb[4];

  auto loadT = [&](int kb){
    ra0 = *(const f4*)(xA + kb*64);
    ra1 = *(const f4*)(xA + kb*64 + 4);
    const u4* p = (const u4*)(wB + kb*64);
    rb[0] = p[0]; rb[1] = p[1]; rb[2] = p[2]; rb[3] = p[3];
  };
  auto writeT = [&](int buf){
    u4 va;
    va.x = f2bf(ra0[0]) | (f2bf(ra0[1]) << 16);
    va.y = f2bf(ra0[2]) | (f2bf(ra0[3]) << 16);
    va.z = f2bf(ra1[0]) | (f2bf(ra1[1]) << 16);
    va.w = f2bf(ra1[2]) | (f2bf(ra1[3]) << 16);
    *(u4*)(lds + buf*G1_ABUF + aoff) = va;
    char* bb = lds + G1_BBASE + buf*G1_BBUF;
    #pragma unroll
    for (int c = 0; c < 4; c++) *(u4*)(bb + bofs[c]) = rb[c];
  };
  auto compute = [&](int buf){
    const char* abuf = lds + buf*G1_ABUF;
    const char* bbuf = lds + G1_BBASE + buf*G1_BBUF;
    const int klo = (lane >> 4) * 8;
    short8 af[2][2], bf[4][2];
    #pragma unroll
    for (int fm = 0; fm < 2; fm++){
      int m = wm*32 + fm*16 + (lane & 15);
      #pragma unroll
      for (int ks = 0; ks < 2; ks++){
        int off = (m*128 + (ks*32 + klo)*2) ^ ((m & 7) << 4);
        af[fm][ks] = *(const short8*)(abuf + off);
      }
    }
    #pragma unroll
    for (int fn = 0; fn < 4; fn++){
      int n = wn*64 + fn*16 + (lane & 15);
      #pragma unroll
      for (int ks = 0; ks < 2; ks++){
        int off = (n*128 + (ks*32 + klo)*2) ^ ((n & 7) << 4);
        bf[fn][ks] = *(const short8*)(bbuf + off);
      }
    }
    #pragma unroll
    for (int ks = 0; ks < 2; ks++)
      #pragma unroll
      for (int fm = 0; fm < 2; fm++)
        #pragma unroll
        for (int fn = 0; fn < 4; fn++)
          acc[fm][fn] = __builtin_amdgcn_mfma_f32_16x16x32_bf16(af[fm][ks], bf[fn][ks], acc[fm][fn], 0, 0, 0);
  };

  loadT(0); writeT(0);
  __syncthreads();
  for (int kb = 0; kb < 64; kb++){
    int cur = kb & 1;
    bool pre = (kb + 1 < 64);
    if (pre) loadT(kb + 1);
    compute(cur);
    if (pre) writeT(cur ^ 1);
    __syncthreads();
  }

  #pragma unroll
  for (int fn = 0; fn < 4; fn++){
    int c = wn*64 + fn*16 + (lane & 15);
    float sb = fsign(b1[c]);
    #pragma unroll
    for (int fm = 0; fm < 2; fm++){
      int rbase = row0 + wm*32 + fm*16 + (lane >> 4)*4;
      #pragma unroll
      for (int i = 0; i < 4; i++)
        h1[(size_t)(rbase + i)*256 + c] = acc[fm][fn][i] + sb;
    }
  }
}

// ---------------- per-block column partial sums (deterministic) ----------------
template<int COLS, int ROWS>
__global__ void stats_k(const float* __restrict__ h, float* __restrict__ part){
  int b = blockIdx.x, t = threadIdx.x;
  const float* p = h + (size_t)b * ROWS * COLS + t;
  float s = 0.f, q = 0.f;
  for (int r = 0; r < ROWS; r++){ float v = p[(size_t)r * COLS]; s += v; q += v * v; }
  part[b * COLS + t] = s;
  part[gridDim.x * COLS + b * COLS + t] = q;
}

template<int COLS, int NBLK>
__global__ void params_k(const float* __restrict__ part, const float* __restrict__ g,
                         const float* __restrict__ be, float* __restrict__ ab, float invB){
  int j = threadIdx.x;
  float s = 0.f, q = 0.f;
  for (int b = 0; b < NBLK; b++){ s += part[b * COLS + j]; q += part[NBLK * COLS + b * COLS + j]; }
  float mu  = s * invB;
  float var = q * invB - mu * mu;
  float a   = g[j] * rsqrtf(var + 1e-5f);
  ab[j] = a;
  ab[COLS + j] = be[j] - mu * a;
}

// ---------------- GEMM2: h2 = clip(BN1(h1)) @ signW2^T + sign(b2) ----------------
// BM=64, BN=128 (full), K=256 (B fully resident), BK=64 for A, 256 thr (4 waves, wave 32x64).
#define G2_ABUF 8192
#define G2_BBASE 16384

__global__ __launch_bounds__(256) void gemm2_k(
    const float* __restrict__ h1, const unsigned short* __restrict__ w2s,
    const float* __restrict__ b2, const float* __restrict__ ab1,
    float* __restrict__ h2)
{
  __shared__ __align__(16) char lds[16384 + 65536];
  __shared__ __align__(16) float a1l[256];
  __shared__ __align__(16) float c1l[256];
  const int tid  = threadIdx.x;
  const int lane = tid & 63;
  const int wid  = tid >> 6;
  const int wm   = wid >> 1, wn = wid & 1;
  const int row0 = blockIdx.x * 64;

  a1l[tid] = ab1[tid];
  c1l[tid] = ab1[256 + tid];

  // stage full B (128x256 bf16, swizzled)
  #pragma unroll
  for (int i = 0; i < 16; i++){
    int c = tid + i * 256;
    int n = c >> 5, j = c & 31;
    u4 v = *(const u4*)(w2s + n*256 + j*8);
    *(u4*)(lds + G2_BBASE + ((n*512 + j*16) ^ ((n & 7) << 4))) = v;
  }

  const int am  = tid >> 2;
  const int ak0 = (tid & 3) * 16;
  const float* hA = h1 + (size_t)(row0 + am) * 256 + ak0;
  const int aw0 = (am*128 + ak0*2 +  0) ^ ((am & 7) << 4);
  const int aw1 = (am*128 + ak0*2 + 16) ^ ((am & 7) << 4);

  __syncthreads();   // a1l/c1l + B visible

  f4 acc[2][4];
  const f4 z = {0.f, 0.f, 0.f, 0.f};
  #pragma unroll
  for (int i = 0; i < 2; i++)
    #pragma unroll
    for (int j = 0; j < 4; j++) acc[i][j] = z;

  f4 r[4];
  auto loadA = [&](int kb){
    #pragma unroll
    for (int j = 0; j < 4; j++) r[j] = *(const f4*)(hA + kb*64 + j*4);
  };
  auto writeA = [&](int buf, int kb){
    unsigned int pk[8];
    #pragma unroll
    for (int j = 0; j < 4; j++){
      f4 av = *(const f4*)(&a1l[kb*64 + ak0 + j*4]);
      f4 cv = *(const f4*)(&c1l[kb*64 + ak0 + j*4]);
      float t0 = hclip(av[0]*r[j][0] + cv[0]);
      float t1 = hclip(av[1]*r[j][1] + cv[1]);
      float t2 = hclip(av[2]*r[j][2] + cv[2]);
      float t3 = hclip(av[3]*r[j][3] + cv[3]);
      pk[2*j]   = f2bf(t0) | (f2bf(t1) << 16);
      pk[2*j+1] = f2bf(t2) | (f2bf(t3) << 16);
    }
    u4 v0; v0.x = pk[0]; v0.y = pk[1]; v0.z = pk[2]; v0.w = pk[3];
    u4 v1; v1.x = pk[4]; v1.y = pk[5]; v1.z = pk[6]; v1.w = pk[7];
    *(u4*)(lds + buf*G2_ABUF + aw0) = v0;
    *(u4*)(lds + buf*G2_ABUF + aw1) = v1;
  };
  auto compute = [&](int buf, int kb){
    const char* abuf = lds + buf*G2_ABUF;
    const char* bbuf = lds + G2_BBASE;
    const int klo = (lane >> 4) * 8;
    short8 af[2][2], bf[4][2];
    #pragma unroll
    for (int fm = 0; fm < 2; fm++){
      int m = wm*32 + fm*16 + (lane & 15);
      #pragma unroll
      for (int ks = 0; ks < 2; ks++){
        int off = (m*128 + (ks*32 + klo)*2) ^ ((m & 7) << 4);
        af[fm][ks] = *(const short8*)(abuf + off);
      }
    }
    #pragma unroll
    for (int fn = 0; fn < 4; fn++){
      int n = wn*64 + fn*16 + (lane & 15);
      #pragma unroll
      for (int ks = 0; ks < 2; ks++){
        int off = (n*512 + (kb*64 + ks*32 + klo)*2) ^ ((n & 7) << 4);
        bf[fn][ks] = *(const short8*)(bbuf + off);
      }
    }
    #pragma unroll
    for (int ks = 0; ks < 2; ks++)
      #pragma unroll
      for (int fm = 0; fm < 2; fm++)
        #pragma unroll
        for (int fn = 0; fn < 4; fn++)
          acc[fm][fn] = __builtin_amdgcn_mfma_f32_16x16x32_bf16(af[fm][ks], bf[fn][ks], acc[fm][fn], 0, 0, 0);
  };

  loadA(0); writeA(0, 0);
  __syncthreads();
  for (int kb = 0; kb < 4; kb++){
    int cur = kb & 1;
    bool pre = (kb + 1 < 4);
    if (pre) loadA(kb + 1);
    compute(cur, kb);
    if (pre) writeA(cur ^ 1, kb + 1);
    __syncthreads();
  }

  #pragma unroll
  for (int fn = 0; fn < 4; fn++){
    int c = wn*64 + fn*16 + (lane & 15);
    float sb = fsign(b2[c]);
    #pragma unroll
    for (int fm = 0; fm < 2; fm++){
      int rbase = row0 + wm*32 + fm*16 + (lane >> 4)*4;
      #pragma unroll
      for (int i = 0; i < 4; i++)
        h2[(size_t)(rbase + i)*128 + c] = acc[fm][fn][i] + sb;
    }
  }
}

// ---------------- final: out = clip(BN2(h2)) @ W4^T + b4  (fp32 VALU, N=12) ----------------
__global__ __launch_bounds__(128) void final_k(
    const float* __restrict__ h2, const float* __restrict__ ab2,
    const float* __restrict__ W4, const float* __restrict__ b4,
    float* __restrict__ out)
{
  __shared__ __align__(16) float W4l[12*128];
  __shared__ __align__(16) float a2l[128];
  __shared__ __align__(16) float c2l[128];
  int t = threadIdx.x;
  for (int i = t; i < 1536; i += 128) W4l[i] = W4[i];
  a2l[t] = ab2[t];
  c2l[t] = ab2[128 + t];
  __syncthreads();

  int r = blockIdx.x * 128 + t;
  const float* hrow = h2 + (size_t)r * 128;
  float acc[12];
  #pragma unroll
  for (int j = 0; j < 12; j++) acc[j] = b4[j];

  #pragma unroll 4
  for (int k = 0; k < 128; k += 4){
    f4 v  = *(const f4*)(hrow + k);
    f4 av = *(const f4*)(&a2l[k]);
    f4 cv = *(const f4*)(&c2l[k]);
    float h0 = hclip(av[0]*v[0] + cv[0]);
    float h1v = hclip(av[1]*v[1] + cv[1]);
    float h2v = hclip(av[2]*v[2] + cv[2]);
    float h3 = hclip(av[3]*v[3] + cv[3]);
    #pragma unroll
    for (int o = 0; o < 12; o++){
      f4 w = *(const f4*)(&W4l[o*128 + k]);
      acc[o] += h0*w[0] + h1v*w[1] + h2v*w[2] + h3*w[3];
    }
  }
  #pragma unroll
  for (int j = 0; j < 12; j++) out[(size_t)r*12 + j] = acc[j];
}

// ---------------- launch ----------------
extern "C" void kernel_launch(void* const* d_in, const int* in_sizes, int n_in,
                              void* d_out, int out_size, void* d_ws, size_t ws_size,
                              hipStream_t stream)
{
  const float* x   = (const float*)d_in[0];
  const float* W1  = (const float*)d_in[1];
  const float* b1  = (const float*)d_in[2];
  const float* g1  = (const float*)d_in[3];
  const float* be1 = (const float*)d_in[4];
  const float* W2  = (const float*)d_in[5];
  const float* b2  = (const float*)d_in[6];
  const float* g2  = (const float*)d_in[7];
  const float* be2 = (const float*)d_in[8];
  const float* W4  = (const float*)d_in[9];
  const float* b4  = (const float*)d_in[10];
  float* out = (float*)d_out;

  char* ws = (char*)d_ws;
  float*          h1    = (float*)(ws);                       // 16 MB  [16384,256]
  float*          h2    = (float*)(ws + 16777216);            //  8 MB  [16384,128]
  unsigned short* w1s   = (unsigned short*)(ws + 25165824);   //  2 MB  [256,4096] bf16
  unsigned short* w2s   = (unsigned short*)(ws + 27262976);   // 64 KB  [128,256] bf16
  float*          part1 = (float*)(ws + 27328512);            // 512 KB
  float*          part2 = (float*)(ws + 27852800);            // 128 KB
  float*          ab1   = (float*)(ws + 27983872);            // a1[256], c1[256]
  float*          ab2   = (float*)(ws + 27985920);            // a2[128], c2[128]

  prep_sign_k<<<512, 256, 0, stream>>>(W1, w1s, 1048576);
  prep_sign_k<<<16, 256, 0, stream>>>(W2, w2s, 32768);
  gemm1_k<<<256, 512, 0, stream>>>(x, w1s, b1, h1);
  stats_k<256, 64><<<256, 256, 0, stream>>>(h1, part1);
  params_k<256, 256><<<1, 256, 0, stream>>>(part1, g1, be1, ab1, 1.f/16384.f);
  gemm2_k<<<256, 256, 0, stream>>>(h1, w2s, b2, ab1, h2);
  stats_k<128, 128><<<128, 128, 0, stream>>>(h2, part2);
  params_k<128, 128><<<1, 128, 0, stream>>>(part2, g2, be2, ab2, 1.f/16384.f);
  final_k<<<128, 128, 0, stream>>>(h2, ab2, W4, b4, out);
}

// Round 2
// 166.890 us; speedup vs baseline: 1.0326x; 1.0326x over previous
//
#include <hip/hip_runtime.h>
#include <cstddef>

typedef __attribute__((ext_vector_type(8))) short short8;
typedef __attribute__((ext_vector_type(4))) float f4;
typedef __attribute__((ext_vector_type(4))) unsigned int u4;

__device__ __forceinline__ unsigned int f2bf(float f){
  unsigned int u = __float_as_uint(f);
  u += 0x7fffu + ((u >> 16) & 1u);   // RNE to bf16
  return u >> 16;
}
__device__ __forceinline__ float fsign(float x){ return (x > 0.f) ? 1.f : ((x < 0.f) ? -1.f : 0.f); }
__device__ __forceinline__ float hclip(float x){ return fminf(1.f, fmaxf(-1.f, x)); }

// ---------------- prep: sign(W1)+sign(W2) fp32 -> bf16 {+1,-1,0}, one dispatch ----------------
__global__ void prep_sign_k(const float* __restrict__ W1, unsigned short* __restrict__ w1s,
                            const float* __restrict__ W2, unsigned short* __restrict__ w2s){
  int i = (blockIdx.x * blockDim.x + threadIdx.x) * 8;
  const float* w; unsigned short* o; int off;
  if (i < 1048576){ w = W1; o = w1s; off = i; }
  else            { w = W2; o = w2s; off = i - 1048576; if (off >= 32768) return; }
  f4 a = *(const f4*)(w + off);
  f4 b = *(const f4*)(w + off + 4);
  unsigned short s[8];
  #pragma unroll
  for (int j = 0; j < 4; j++) s[j]   = (a[j] > 0.f) ? 0x3F80u : ((a[j] < 0.f) ? 0xBF80u : 0u);
  #pragma unroll
  for (int j = 0; j < 4; j++) s[4+j] = (b[j] > 0.f) ? 0x3F80u : ((b[j] < 0.f) ? 0xBF80u : 0u);
  u4 v;
  v.x = (unsigned)s[0] | ((unsigned)s[1] << 16);
  v.y = (unsigned)s[2] | ((unsigned)s[3] << 16);
  v.z = (unsigned)s[4] | ((unsigned)s[5] << 16);
  v.w = (unsigned)s[6] | ((unsigned)s[7] << 16);
  *(u4*)(o + off) = v;
}

// ---------------- GEMM1: h1[16384,256] = x @ signW1^T + sign(b1), fused col-stats ----------------
// BM=64, BN=256, BK=64, 512 thr (8 waves, wave 32x64), dbuf LDS + XOR swizzle,
// depth-3 global prefetch (4 static register slots).
#define G1_ABUF 8192
#define G1_BBASE 16384
#define G1_BBUF 32768

__global__ __launch_bounds__(512) void gemm1_k(
    const float* __restrict__ x, const unsigned short* __restrict__ w1s,
    const float* __restrict__ b1, float* __restrict__ h1, float* __restrict__ part1)
{
  __shared__ __align__(16) char lds[81920];
  const int tid  = threadIdx.x;
  const int lane = tid & 63;
  const int wid  = tid >> 6;
  const int wm   = wid >> 2, wn = wid & 3;
  const int row0 = blockIdx.x * 64;

  // A staging: thread -> row am, 8 contiguous k at ak0
  const int am  = tid >> 3;
  const int ak0 = (tid & 7) * 8;
  const float* xA = x + (size_t)(row0 + am) * 4096 + ak0;
  const int aoff  = ((am * 128) + (ak0 * 2)) ^ ((am & 7) << 4);

  // B staging: thread -> n row bn, 32 contiguous bf16 at bk0
  const int bn  = tid >> 1;
  const int bk0 = (tid & 1) * 32;
  const unsigned short* wB = w1s + bn * 4096 + bk0;
  const int bofs0 = (bn*128 + bk0*2 +  0) ^ ((bn & 7) << 4);
  const int bofs1 = (bn*128 + bk0*2 + 16) ^ ((bn & 7) << 4);
  const int bofs2 = (bn*128 + bk0*2 + 32) ^ ((bn & 7) << 4);
  const int bofs3 = (bn*128 + bk0*2 + 48) ^ ((bn & 7) << 4);

  f4 acc[2][4];
  const f4 z = {0.f, 0.f, 0.f, 0.f};
  #pragma unroll
  for (int i = 0; i < 2; i++)
    #pragma unroll
    for (int j = 0; j < 4; j++) acc[i][j] = z;

  // 4 static prefetch slots
  f4 ra00, ra01, ra10, ra11, ra20, ra21, ra30, ra31;
  u4 rb00, rb01, rb02, rb03, rb10, rb11, rb12, rb13;
  u4 rb20, rb21, rb22, rb23, rb30, rb31, rb32, rb33;

#define LOADT(S, KB) do { \
    ra##S##0 = *(const f4*)(xA + (KB)*64); \
    ra##S##1 = *(const f4*)(xA + (KB)*64 + 4); \
    const u4* _p = (const u4*)(wB + (KB)*64); \
    rb##S##0 = _p[0]; rb##S##1 = _p[1]; rb##S##2 = _p[2]; rb##S##3 = _p[3]; \
  } while(0)

#define WRITET(S, BUF) do { \
    u4 _va; \
    _va.x = f2bf(ra##S##0[0]) | (f2bf(ra##S##0[1]) << 16); \
    _va.y = f2bf(ra##S##0[2]) | (f2bf(ra##S##0[3]) << 16); \
    _va.z = f2bf(ra##S##1[0]) | (f2bf(ra##S##1[1]) << 16); \
    _va.w = f2bf(ra##S##1[2]) | (f2bf(ra##S##1[3]) << 16); \
    *(u4*)(lds + (BUF)*G1_ABUF + aoff) = _va; \
    char* _bb = lds + G1_BBASE + (BUF)*G1_BBUF; \
    *(u4*)(_bb + bofs0) = rb##S##0; \
    *(u4*)(_bb + bofs1) = rb##S##1; \
    *(u4*)(_bb + bofs2) = rb##S##2; \
    *(u4*)(_bb + bofs3) = rb##S##3; \
  } while(0)

  auto compute = [&](int buf){
    const char* abuf = lds + buf*G1_ABUF;
    const char* bbuf = lds + G1_BBASE + buf*G1_BBUF;
    const int klo = (lane >> 4) * 8;
    short8 af[2][2], bf[4][2];
    #pragma unroll
    for (int fm = 0; fm < 2; fm++){
      int m = wm*32 + fm*16 + (lane & 15);
      #pragma unroll
      for (int ks = 0; ks < 2; ks++){
        int off = (m*128 + (ks*32 + klo)*2) ^ ((m & 7) << 4);
        af[fm][ks] = *(const short8*)(abuf + off);
      }
    }
    #pragma unroll
    for (int fn = 0; fn < 4; fn++){
      int n = wn*64 + fn*16 + (lane & 15);
      #pragma unroll
      for (int ks = 0; ks < 2; ks++){
        int off = (n*128 + (ks*32 + klo)*2) ^ ((n & 7) << 4);
        bf[fn][ks] = *(const short8*)(bbuf + off);
      }
    }
    #pragma unroll
    for (int ks = 0; ks < 2; ks++)
      #pragma unroll
      for (int fm = 0; fm < 2; fm++)
        #pragma unroll
        for (int fn = 0; fn < 4; fn++)
          acc[fm][fn] = __builtin_amdgcn_mfma_f32_16x16x32_bf16(af[fm][ks], bf[fn][ks], acc[fm][fn], 0, 0, 0);
  };

  LOADT(0, 0); LOADT(1, 1); LOADT(2, 2);
  WRITET(0, 0);
  __syncthreads();
  for (int t = 0; t < 64; t += 4){
    LOADT(3, t+3);                       // t <= 60 -> t+3 <= 63, always valid
    compute(0);
    WRITET(1, 1);
    __syncthreads();
    if (t+4 < 64) LOADT(0, t+4);
    compute(1);
    WRITET(2, 0);
    __syncthreads();
    if (t+5 < 64) LOADT(1, t+5);
    compute(0);
    WRITET(3, 1);
    __syncthreads();
    if (t+6 < 64) LOADT(2, t+6);
    compute(1);
    if (t+4 < 64) WRITET(0, 0);
    __syncthreads();
  }
#undef LOADT
#undef WRITET

  // epilogue: h1 write + fused column stats (deterministic fixed-order)
  #pragma unroll
  for (int fn = 0; fn < 4; fn++){
    int c = wn*64 + fn*16 + (lane & 15);
    float sb = fsign(b1[c]);
    float s = 0.f, q = 0.f;
    #pragma unroll
    for (int fm = 0; fm < 2; fm++){
      int rbase = row0 + wm*32 + fm*16 + (lane >> 4)*4;
      #pragma unroll
      for (int i = 0; i < 4; i++){
        float v = acc[fm][fn][i] + sb;
        h1[(size_t)(rbase + i)*256 + c] = v;
        s += v; q += v*v;
      }
    }
    s += __shfl_xor(s, 16, 64); s += __shfl_xor(s, 32, 64);
    q += __shfl_xor(q, 16, 64); q += __shfl_xor(q, 32, 64);
    if ((lane >> 4) == 0){
      part1[(blockIdx.x*2 + wm)*256 + c] = s;
      part1[131072 + (blockIdx.x*2 + wm)*256 + c] = q;
    }
  }
}

// ---------------- BN params from partials ----------------
template<int COLS, int NBLK>
__global__ void params_k(const float* __restrict__ part, const float* __restrict__ g,
                         const float* __restrict__ be, float* __restrict__ ab, float invB){
  int j = threadIdx.x;
  float s = 0.f, q = 0.f;
  for (int b = 0; b < NBLK; b++){ s += part[b * COLS + j]; q += part[NBLK * COLS + b * COLS + j]; }
  float mu  = s * invB;
  float var = q * invB - mu * mu;
  float a   = g[j] * rsqrtf(var + 1e-5f);
  ab[j] = a;
  ab[COLS + j] = be[j] - mu * a;
}

// ---------------- GEMM2: h2 = clip(BN1(h1)) @ signW2^T + sign(b2), fused col-stats ----------------
#define G2_ABUF 8192
#define G2_BBASE 16384

__global__ __launch_bounds__(256) void gemm2_k(
    const float* __restrict__ h1, const unsigned short* __restrict__ w2s,
    const float* __restrict__ b2, const float* __restrict__ ab1,
    float* __restrict__ h2, float* __restrict__ part2)
{
  __shared__ __align__(16) char lds[16384 + 65536];
  __shared__ __align__(16) float a1l[256];
  __shared__ __align__(16) float c1l[256];
  const int tid  = threadIdx.x;
  const int lane = tid & 63;
  const int wid  = tid >> 6;
  const int wm   = wid >> 1, wn = wid & 1;
  const int row0 = blockIdx.x * 64;

  a1l[tid] = ab1[tid];
  c1l[tid] = ab1[256 + tid];

  // stage full B (128x256 bf16, swizzled)
  #pragma unroll
  for (int i = 0; i < 16; i++){
    int c = tid + i * 256;
    int n = c >> 5, j = c & 31;
    u4 v = *(const u4*)(w2s + n*256 + j*8);
    *(u4*)(lds + G2_BBASE + ((n*512 + j*16) ^ ((n & 7) << 4))) = v;
  }

  const int am  = tid >> 2;
  const int ak0 = (tid & 3) * 16;
  const float* hA = h1 + (size_t)(row0 + am) * 256 + ak0;
  const int aw0 = (am*128 + ak0*2 +  0) ^ ((am & 7) << 4);
  const int aw1 = (am*128 + ak0*2 + 16) ^ ((am & 7) << 4);

  __syncthreads();   // a1l/c1l + B visible

  f4 acc[2][4];
  const f4 z = {0.f, 0.f, 0.f, 0.f};
  #pragma unroll
  for (int i = 0; i < 2; i++)
    #pragma unroll
    for (int j = 0; j < 4; j++) acc[i][j] = z;

  f4 r[4];
  auto loadA = [&](int kb){
    #pragma unroll
    for (int j = 0; j < 4; j++) r[j] = *(const f4*)(hA + kb*64 + j*4);
  };
  auto writeA = [&](int buf, int kb){
    unsigned int pk[8];
    #pragma unroll
    for (int j = 0; j < 4; j++){
      f4 av = *(const f4*)(&a1l[kb*64 + ak0 + j*4]);
      f4 cv = *(const f4*)(&c1l[kb*64 + ak0 + j*4]);
      float t0 = hclip(av[0]*r[j][0] + cv[0]);
      float t1 = hclip(av[1]*r[j][1] + cv[1]);
      float t2 = hclip(av[2]*r[j][2] + cv[2]);
      float t3 = hclip(av[3]*r[j][3] + cv[3]);
      pk[2*j]   = f2bf(t0) | (f2bf(t1) << 16);
      pk[2*j+1] = f2bf(t2) | (f2bf(t3) << 16);
    }
    u4 v0; v0.x = pk[0]; v0.y = pk[1]; v0.z = pk[2]; v0.w = pk[3];
    u4 v1; v1.x = pk[4]; v1.y = pk[5]; v1.z = pk[6]; v1.w = pk[7];
    *(u4*)(lds + buf*G2_ABUF + aw0) = v0;
    *(u4*)(lds + buf*G2_ABUF + aw1) = v1;
  };
  auto compute = [&](int buf, int kb){
    const char* abuf = lds + buf*G2_ABUF;
    const char* bbuf = lds + G2_BBASE;
    const int klo = (lane >> 4) * 8;
    short8 af[2][2], bf[4][2];
    #pragma unroll
    for (int fm = 0; fm < 2; fm++){
      int m = wm*32 + fm*16 + (lane & 15);
      #pragma unroll
      for (int ks = 0; ks < 2; ks++){
        int off = (m*128 + (ks*32 + klo)*2) ^ ((m & 7) << 4);
        af[fm][ks] = *(const short8*)(abuf + off);
      }
    }
    #pragma unroll
    for (int fn = 0; fn < 4; fn++){
      int n = wn*64 + fn*16 + (lane & 15);
      #pragma unroll
      for (int ks = 0; ks < 2; ks++){
        int off = (n*512 + (kb*64 + ks*32 + klo)*2) ^ ((n & 7) << 4);
        bf[fn][ks] = *(const short8*)(bbuf + off);
      }
    }
    #pragma unroll
    for (int ks = 0; ks < 2; ks++)
      #pragma unroll
      for (int fm = 0; fm < 2; fm++)
        #pragma unroll
        for (int fn = 0; fn < 4; fn++)
          acc[fm][fn] = __builtin_amdgcn_mfma_f32_16x16x32_bf16(af[fm][ks], bf[fn][ks], acc[fm][fn], 0, 0, 0);
  };

  loadA(0); writeA(0, 0);
  __syncthreads();
  for (int kb = 0; kb < 4; kb++){
    int cur = kb & 1;
    bool pre = (kb + 1 < 4);
    if (pre) loadA(kb + 1);
    compute(cur, kb);
    if (pre) writeA(cur ^ 1, kb + 1);
    __syncthreads();
  }

  #pragma unroll
  for (int fn = 0; fn < 4; fn++){
    int c = wn*64 + fn*16 + (lane & 15);
    float sb = fsign(b2[c]);
    float s = 0.f, q = 0.f;
    #pragma unroll
    for (int fm = 0; fm < 2; fm++){
      int rbase = row0 + wm*32 + fm*16 + (lane >> 4)*4;
      #pragma unroll
      for (int i = 0; i < 4; i++){
        float v = acc[fm][fn][i] + sb;
        h2[(size_t)(rbase + i)*128 + c] = v;
        s += v; q += v*v;
      }
    }
    s += __shfl_xor(s, 16, 64); s += __shfl_xor(s, 32, 64);
    q += __shfl_xor(q, 16, 64); q += __shfl_xor(q, 32, 64);
    if ((lane >> 4) == 0){
      part2[(blockIdx.x*2 + wm)*128 + c] = s;
      part2[65536 + (blockIdx.x*2 + wm)*128 + c] = q;
    }
  }
}

// ---------------- final: out = clip(BN2(h2)) @ W4^T + b4  (fp32 VALU, N=12) ----------------
__global__ __launch_bounds__(128) void final_k(
    const float* __restrict__ h2, const float* __restrict__ ab2,
    const float* __restrict__ W4, const float* __restrict__ b4,
    float* __restrict__ out)
{
  __shared__ __align__(16) float W4l[12*128];
  __shared__ __align__(16) float a2l[128];
  __shared__ __align__(16) float c2l[128];
  int t = threadIdx.x;
  for (int i = t; i < 1536; i += 128) W4l[i] = W4[i];
  a2l[t] = ab2[t];
  c2l[t] = ab2[128 + t];
  __syncthreads();

  int r = blockIdx.x * 128 + t;
  const float* hrow = h2 + (size_t)r * 128;
  float acc[12];
  #pragma unroll
  for (int j = 0; j < 12; j++) acc[j] = b4[j];

  #pragma unroll 4
  for (int k = 0; k < 128; k += 4){
    f4 v  = *(const f4*)(hrow + k);
    f4 av = *(const f4*)(&a2l[k]);
    f4 cv = *(const f4*)(&c2l[k]);
    float h0 = hclip(av[0]*v[0] + cv[0]);
    float h1v = hclip(av[1]*v[1] + cv[1]);
    float h2v = hclip(av[2]*v[2] + cv[2]);
    float h3 = hclip(av[3]*v[3] + cv[3]);
    #pragma unroll
    for (int o = 0; o < 12; o++){
      f4 w = *(const f4*)(&W4l[o*128 + k]);
      acc[o] += h0*w[0] + h1v*w[1] + h2v*w[2] + h3*w[3];
    }
  }
  #pragma unroll
  for (int j = 0; j < 12; j++) out[(size_t)r*12 + j] = acc[j];
}

// ---------------- launch ----------------
extern "C" void kernel_launch(void* const* d_in, const int* in_sizes, int n_in,
                              void* d_out, int out_size, void* d_ws, size_t ws_size,
                              hipStream_t stream)
{
  const float* x   = (const float*)d_in[0];
  const float* W1  = (const float*)d_in[1];
  const float* b1  = (const float*)d_in[2];
  const float* g1  = (const float*)d_in[3];
  const float* be1 = (const float*)d_in[4];
  const float* W2  = (const float*)d_in[5];
  const float* b2  = (const float*)d_in[6];
  const float* g2  = (const float*)d_in[7];
  const float* be2 = (const float*)d_in[8];
  const float* W4  = (const float*)d_in[9];
  const float* b4  = (const float*)d_in[10];
  float* out = (float*)d_out;

  char* ws = (char*)d_ws;
  float*          h1    = (float*)(ws);                       // 16 MB  [16384,256]
  float*          h2    = (float*)(ws + 16777216);            //  8 MB  [16384,128]
  unsigned short* w1s   = (unsigned short*)(ws + 25165824);   //  2 MB  [256,4096] bf16
  unsigned short* w2s   = (unsigned short*)(ws + 27262976);   // 64 KB  [128,256] bf16
  float*          part1 = (float*)(ws + 27328512);            //  1 MB  (2 x 512 x 256)
  float*          part2 = (float*)(ws + 28377088);            // 512 KB (2 x 512 x 128)
  float*          ab1   = (float*)(ws + 28901376);            // a1[256], c1[256]
  float*          ab2   = (float*)(ws + 28903424);            // a2[128], c2[128]

  prep_sign_k<<<528, 256, 0, stream>>>(W1, w1s, W2, w2s);
  gemm1_k<<<256, 512, 0, stream>>>(x, w1s, b1, h1, part1);
  params_k<256, 512><<<1, 256, 0, stream>>>(part1, g1, be1, ab1, 1.f/16384.f);
  gemm2_k<<<256, 256, 0, stream>>>(h1, w2s, b2, ab1, h2, part2);
  params_k<128, 512><<<1, 128, 0, stream>>>(part2, g2, be2, ab2, 1.f/16384.f);
  final_k<<<128, 128, 0, stream>>>(h2, ab2, W4, b4, out);
}

// Round 3
// 156.872 us; speedup vs baseline: 1.0985x; 1.0639x over previous
//
#include <hip/hip_runtime.h>
#include <cstddef>

typedef __attribute__((ext_vector_type(8))) short short8;
typedef __attribute__((ext_vector_type(4))) float f4;
typedef __attribute__((ext_vector_type(4))) unsigned int u4;

__device__ __forceinline__ unsigned int f2bf(float f){
  unsigned int u = __float_as_uint(f);
  u += 0x7fffu + ((u >> 16) & 1u);   // RNE to bf16
  return u >> 16;
}
__device__ __forceinline__ float fsign(float x){ return (x > 0.f) ? 1.f : ((x < 0.f) ? -1.f : 0.f); }
__device__ __forceinline__ float hclip(float x){ return fminf(1.f, fmaxf(-1.f, x)); }

// ---------------- prep: sign(W1)+sign(W2) fp32 -> bf16 {+1,-1,0}, one dispatch ----------------
__global__ void prep_sign_k(const float* __restrict__ W1, unsigned short* __restrict__ w1s,
                            const float* __restrict__ W2, unsigned short* __restrict__ w2s){
  int i = (blockIdx.x * blockDim.x + threadIdx.x) * 8;
  const float* w; unsigned short* o; int off;
  if (i < 1048576){ w = W1; o = w1s; off = i; }
  else            { w = W2; o = w2s; off = i - 1048576; if (off >= 32768) return; }
  f4 a = *(const f4*)(w + off);
  f4 b = *(const f4*)(w + off + 4);
  unsigned short s[8];
  #pragma unroll
  for (int j = 0; j < 4; j++) s[j]   = (a[j] > 0.f) ? 0x3F80u : ((a[j] < 0.f) ? 0xBF80u : 0u);
  #pragma unroll
  for (int j = 0; j < 4; j++) s[4+j] = (b[j] > 0.f) ? 0x3F80u : ((b[j] < 0.f) ? 0xBF80u : 0u);
  u4 v;
  v.x = (unsigned)s[0] | ((unsigned)s[1] << 16);
  v.y = (unsigned)s[2] | ((unsigned)s[3] << 16);
  v.z = (unsigned)s[4] | ((unsigned)s[5] << 16);
  v.w = (unsigned)s[6] | ((unsigned)s[7] << 16);
  *(u4*)(o + off) = v;
}

// ---------------- GEMM1: h1(bf16) = x @ signW1^T + sign(b1), fused transposed col-stats ----------
// BM=64, BN=256, BK=64, 512 thr = 8 waves, wave tile 64x32 (no B duplication).
// A-only LDS (2 x 8KB dbuf, XOR swizzle); B direct from global (L2-resident, 2MB).
// Depth-2 A register prefetch, 4 rotating slots; B-loads pinned before A-prefetch issue.
__global__ __launch_bounds__(512) void gemm1_k(
    const float* __restrict__ x, const unsigned short* __restrict__ w1s,
    const float* __restrict__ b1, unsigned short* __restrict__ h1,
    float* __restrict__ part1s, float* __restrict__ part1q)
{
  __shared__ __align__(16) char lds[16384];
  const int tid  = threadIdx.x;
  const int lane = tid & 63;
  const int wid  = tid >> 6;          // 0..7, wave tile rows 0..63 x cols wid*32..+31
  const int cl   = lane & 15;
  const int g    = lane >> 4;         // 0..3
  const int klo  = g * 8;
  const int row0 = blockIdx.x * 64;

  // A staging: thread -> row am, 8 contiguous k at ak0
  const int am  = tid >> 3;
  const int ak0 = (tid & 7) * 8;
  const float* xA = x + (size_t)(row0 + am) * 4096 + ak0;
  const int aoff  = ((am * 128) + (ak0 * 2)) ^ ((am & 7) << 4);

  // B direct-load base: row n = wid*32 + cl (+16 for fn=1), k = klo + kb*64 + ks*32
  const unsigned short* wbase = w1s + (size_t)(wid * 32 + cl) * 4096 + klo;

  f4 acc[4][2];
  const f4 z = {0.f, 0.f, 0.f, 0.f};
  #pragma unroll
  for (int i = 0; i < 4; i++){ acc[i][0] = z; acc[i][1] = z; }

  f4 ra0a, ra0b, ra1a, ra1b, ra2a, ra2b, ra3a, ra3b;

#define LOADT(S, KB) do { \
    ra##S##a = *(const f4*)(xA + (KB)*64); \
    ra##S##b = *(const f4*)(xA + (KB)*64 + 4); \
  } while(0)

#define WRITET(S, BUF) do { \
    u4 _va; \
    _va.x = f2bf(ra##S##a[0]) | (f2bf(ra##S##a[1]) << 16); \
    _va.y = f2bf(ra##S##a[2]) | (f2bf(ra##S##a[3]) << 16); \
    _va.z = f2bf(ra##S##b[0]) | (f2bf(ra##S##b[1]) << 16); \
    _va.w = f2bf(ra##S##b[2]) | (f2bf(ra##S##b[3]) << 16); \
    *(u4*)(lds + (BUF)*8192 + aoff) = _va; \
  } while(0)

  auto compute = [&](int buf, int kb){
    // B loads first (program order matters for in-order vmcnt)
    short8 bf[2][2];
    #pragma unroll
    for (int fn = 0; fn < 2; fn++)
      #pragma unroll
      for (int ks = 0; ks < 2; ks++)
        bf[fn][ks] = *(const short8*)(wbase + fn*65536 + kb*64 + ks*32);
    const char* abuf = lds + buf*8192;
    short8 af[4][2];
    #pragma unroll
    for (int fm = 0; fm < 4; fm++){
      int m = fm*16 + cl;
      #pragma unroll
      for (int ks = 0; ks < 2; ks++){
        int off = (m*128 + (ks*32 + klo)*2) ^ ((m & 7) << 4);
        af[fm][ks] = *(const short8*)(abuf + off);
      }
    }
    #pragma unroll
    for (int ks = 0; ks < 2; ks++)
      #pragma unroll
      for (int fm = 0; fm < 4; fm++)
        #pragma unroll
        for (int fn = 0; fn < 2; fn++)
          acc[fm][fn] = __builtin_amdgcn_mfma_f32_16x16x32_bf16(af[fm][ks], bf[fn][ks], acc[fm][fn], 0, 0, 0);
  };

#define SUBSTEP(BUF, KB, LS, LKB, LGUARD, WS, WBUF, WGUARD) do { \
    compute(BUF, KB); \
    __builtin_amdgcn_sched_barrier(0); \
    if (LGUARD) LOADT(LS, LKB); \
    __builtin_amdgcn_sched_barrier(0); \
    if (WGUARD) WRITET(WS, WBUF); \
    __syncthreads(); \
  } while(0)

  LOADT(0, 0); LOADT(1, 1); LOADT(2, 2);
  WRITET(0, 0);
  __syncthreads();
  for (int t = 0; t < 64; t += 4){
    SUBSTEP(0, t+0, 3, t+3, true,     1, 1, true);
    SUBSTEP(1, t+1, 0, t+4, t+4 < 64, 2, 0, true);
    SUBSTEP(0, t+2, 1, t+5, t+5 < 64, 3, 1, true);
    SUBSTEP(1, t+3, 2, t+6, t+6 < 64, 0, 0, t+4 < 64);
  }
#undef SUBSTEP
#undef LOADT
#undef WRITET

  // epilogue: bf16 h1 write + fused transposed column stats
  #pragma unroll
  for (int fn = 0; fn < 2; fn++){
    int c = wid*32 + fn*16 + cl;
    float sb = fsign(b1[c]);
    float s = 0.f, q = 0.f;
    #pragma unroll
    for (int fm = 0; fm < 4; fm++){
      int rbase = row0 + fm*16 + g*4;
      #pragma unroll
      for (int i = 0; i < 4; i++){
        float v = acc[fm][fn][i] + sb;
        h1[(size_t)(rbase + i)*256 + c] = (unsigned short)f2bf(v);
        s += v; q += v*v;
      }
    }
    s += __shfl_xor(s, 16, 64); s += __shfl_xor(s, 32, 64);
    q += __shfl_xor(q, 16, 64); q += __shfl_xor(q, 32, 64);
    if (g == 0){
      part1s[c*256 + blockIdx.x] = s;
      part1q[c*256 + blockIdx.x] = q;
    }
  }
}

// ---------------- BN params from transposed partials (contiguous per-thread reads) -------------
template<int COLS>
__global__ void params_k(const float* __restrict__ ps, const float* __restrict__ pq,
                         const float* __restrict__ g, const float* __restrict__ be,
                         float* __restrict__ ab){
  int j = threadIdx.x;
  const f4* vs = (const f4*)(ps + j*256);
  const f4* vq = (const f4*)(pq + j*256);
  f4 s4 = {0,0,0,0}, q4 = {0,0,0,0};
  #pragma unroll 8
  for (int b = 0; b < 64; b++){ s4 += vs[b]; q4 += vq[b]; }
  float s = s4[0]+s4[1]+s4[2]+s4[3];
  float q = q4[0]+q4[1]+q4[2]+q4[3];
  float mu  = s * (1.f/16384.f);
  float var = q * (1.f/16384.f) - mu*mu;
  float a   = g[j] * rsqrtf(var + 1e-5f);
  ab[j] = a;
  ab[COLS + j] = be[j] - mu*a;
}

// ---------------- GEMM2: h2(bf16) = clip(BN1(h1)) @ signW2^T + sign(b2), fused stats -----------
// BM=64, BN=128, K=256 (4 steps), 512 thr = 8 waves, wave tile 64x16 (no B duplication).
// A-only LDS dbuf (2 x 8KB), B direct from global (64KB, L2-hot). BN fused into A staging.
__global__ __launch_bounds__(512) void gemm2_k(
    const unsigned short* __restrict__ h1, const unsigned short* __restrict__ w2s,
    const float* __restrict__ b2, const float* __restrict__ ab1,
    unsigned short* __restrict__ h2, float* __restrict__ part2s, float* __restrict__ part2q)
{
  __shared__ __align__(16) char lds[16384];
  __shared__ __align__(16) float a1l[256];
  __shared__ __align__(16) float c1l[256];
  const int tid  = threadIdx.x;
  const int lane = tid & 63;
  const int wid  = tid >> 6;          // 0..7 -> cols wid*16..+15
  const int cl   = lane & 15;
  const int g    = lane >> 4;
  const int klo  = g * 8;
  const int row0 = blockIdx.x * 64;

  if (tid < 256) a1l[tid] = ab1[tid];
  else           c1l[tid - 256] = ab1[tid];

  const int am  = tid >> 3;
  const int ak0 = (tid & 7) * 8;
  const unsigned short* hA = h1 + (size_t)(row0 + am) * 256 + ak0;
  const int aw = ((am * 128) + (ak0 * 2)) ^ ((am & 7) << 4);

  const unsigned short* wbase = w2s + (size_t)(wid * 16 + cl) * 256 + klo;

  f4 acc[4];
  const f4 z = {0.f, 0.f, 0.f, 0.f};
  #pragma unroll
  for (int i = 0; i < 4; i++) acc[i] = z;

  auto writeA = [&](int buf, int kb, u4 raw){
    f4 a0 = *(const f4*)&a1l[kb*64 + ak0];
    f4 a1 = *(const f4*)&a1l[kb*64 + ak0 + 4];
    f4 c0 = *(const f4*)&c1l[kb*64 + ak0];
    f4 c1 = *(const f4*)&c1l[kb*64 + ak0 + 4];
    float t0 = hclip(a0[0]*__uint_as_float((raw.x & 0xFFFFu) << 16) + c0[0]);
    float t1 = hclip(a0[1]*__uint_as_float( raw.x & 0xFFFF0000u   ) + c0[1]);
    float t2 = hclip(a0[2]*__uint_as_float((raw.y & 0xFFFFu) << 16) + c0[2]);
    float t3 = hclip(a0[3]*__uint_as_float( raw.y & 0xFFFF0000u   ) + c0[3]);
    float t4 = hclip(a1[0]*__uint_as_float((raw.z & 0xFFFFu) << 16) + c1[0]);
    float t5 = hclip(a1[1]*__uint_as_float( raw.z & 0xFFFF0000u   ) + c1[1]);
    float t6 = hclip(a1[2]*__uint_as_float((raw.w & 0xFFFFu) << 16) + c1[2]);
    float t7 = hclip(a1[3]*__uint_as_float( raw.w & 0xFFFF0000u   ) + c1[3]);
    u4 v;
    v.x = f2bf(t0) | (f2bf(t1) << 16);
    v.y = f2bf(t2) | (f2bf(t3) << 16);
    v.z = f2bf(t4) | (f2bf(t5) << 16);
    v.w = f2bf(t6) | (f2bf(t7) << 16);
    *(u4*)(lds + buf*8192 + aw) = v;
  };
  auto compute = [&](int buf, int kb){
    short8 bf[2];
    #pragma unroll
    for (int ks = 0; ks < 2; ks++)
      bf[ks] = *(const short8*)(wbase + kb*64 + ks*32);
    const char* abuf = lds + buf*8192;
    short8 af[4][2];
    #pragma unroll
    for (int fm = 0; fm < 4; fm++){
      int m = fm*16 + cl;
      #pragma unroll
      for (int ks = 0; ks < 2; ks++){
        int off = (m*128 + (ks*32 + klo)*2) ^ ((m & 7) << 4);
        af[fm][ks] = *(const short8*)(abuf + off);
      }
    }
    #pragma unroll
    for (int ks = 0; ks < 2; ks++)
      #pragma unroll
      for (int fm = 0; fm < 4; fm++)
        acc[fm] = __builtin_amdgcn_mfma_f32_16x16x32_bf16(af[fm][ks], bf[ks], acc[fm], 0, 0, 0);
  };

  u4 raw0 = *(const u4*)(hA);
  __syncthreads();                 // a1l/c1l visible
  writeA(0, 0, raw0);
  __syncthreads();
  #pragma unroll
  for (int kb = 0; kb < 4; kb++){
    u4 rawn;
    if (kb < 3) rawn = *(const u4*)(hA + (kb+1)*64);
    compute(kb & 1, kb);
    if (kb < 3) writeA((kb+1) & 1, kb+1, rawn);
    __syncthreads();
  }

  #pragma unroll
  for (int fm = 0; fm < 4; fm++){
    // defer to single loop below
  }
  {
    int c = wid*16 + cl;
    float sb = fsign(b2[c]);
    float s = 0.f, q = 0.f;
    #pragma unroll
    for (int fm = 0; fm < 4; fm++){
      int rbase = row0 + fm*16 + g*4;
      #pragma unroll
      for (int i = 0; i < 4; i++){
        float v = acc[fm][i] + sb;
        h2[(size_t)(rbase + i)*128 + c] = (unsigned short)f2bf(v);
        s += v; q += v*v;
      }
    }
    s += __shfl_xor(s, 16, 64); s += __shfl_xor(s, 32, 64);
    q += __shfl_xor(q, 16, 64); q += __shfl_xor(q, 32, 64);
    if (g == 0){
      part2s[c*256 + blockIdx.x] = s;
      part2q[c*256 + blockIdx.x] = q;
    }
  }
}

// ---------------- final: out = clip(BN2(h2)) @ W4^T + b4  (fp32 VALU, N=12) --------------------
// 256 blocks x 64 threads, thread-per-row, 16 u4 row loads fully unrolled.
__global__ __launch_bounds__(64) void final_k(
    const unsigned short* __restrict__ h2, const float* __restrict__ ab2,
    const float* __restrict__ W4, const float* __restrict__ b4,
    float* __restrict__ out)
{
  __shared__ __align__(16) float W4l[12*128];
  __shared__ __align__(16) float a2l[128];
  __shared__ __align__(16) float c2l[128];
  const int t = threadIdx.x;
  #pragma unroll
  for (int i = 0; i < 6; i++)
    *(f4*)&W4l[(i*64 + t)*4] = *(const f4*)(W4 + (i*64 + t)*4);
  a2l[t]      = ab2[t];
  a2l[t + 64] = ab2[t + 64];
  c2l[t]      = ab2[128 + t];
  c2l[t + 64] = ab2[192 + t];
  __syncthreads();

  const int r = blockIdx.x * 64 + t;
  const u4* hp = (const u4*)(h2 + (size_t)r * 128);
  u4 hv0 = hp[0], hv1 = hp[1], hv2 = hp[2],  hv3 = hp[3];
  u4 hv4 = hp[4], hv5 = hp[5], hv6 = hp[6],  hv7 = hp[7];
  u4 hv8 = hp[8], hv9 = hp[9], hv10 = hp[10], hv11 = hp[11];
  u4 hv12 = hp[12], hv13 = hp[13], hv14 = hp[14], hv15 = hp[15];

  float acc[12];
  #pragma unroll
  for (int o = 0; o < 12; o++) acc[o] = b4[o];

#define FPROC(HV, J) do { \
    f4 a0 = *(const f4*)&a2l[(J)*8];     f4 a1 = *(const f4*)&a2l[(J)*8 + 4]; \
    f4 c0 = *(const f4*)&c2l[(J)*8];     f4 c1 = *(const f4*)&c2l[(J)*8 + 4]; \
    float tt0 = hclip(a0[0]*__uint_as_float((HV.x & 0xFFFFu) << 16) + c0[0]); \
    float tt1 = hclip(a0[1]*__uint_as_float( HV.x & 0xFFFF0000u   ) + c0[1]); \
    float tt2 = hclip(a0[2]*__uint_as_float((HV.y & 0xFFFFu) << 16) + c0[2]); \
    float tt3 = hclip(a0[3]*__uint_as_float( HV.y & 0xFFFF0000u   ) + c0[3]); \
    float tt4 = hclip(a1[0]*__uint_as_float((HV.z & 0xFFFFu) << 16) + c1[0]); \
    float tt5 = hclip(a1[1]*__uint_as_float( HV.z & 0xFFFF0000u   ) + c1[1]); \
    float tt6 = hclip(a1[2]*__uint_as_float((HV.w & 0xFFFFu) << 16) + c1[2]); \
    float tt7 = hclip(a1[3]*__uint_as_float( HV.w & 0xFFFF0000u   ) + c1[3]); \
    _Pragma("unroll") \
    for (int o = 0; o < 12; o++){ \
      f4 w0 = *(const f4*)&W4l[o*128 + (J)*8]; \
      f4 w1 = *(const f4*)&W4l[o*128 + (J)*8 + 4]; \
      acc[o] += tt0*w0[0] + tt1*w0[1] + tt2*w0[2] + tt3*w0[3] \
              + tt4*w1[0] + tt5*w1[1] + tt6*w1[2] + tt7*w1[3]; \
    } \
  } while(0)

  FPROC(hv0, 0);  FPROC(hv1, 1);  FPROC(hv2, 2);   FPROC(hv3, 3);
  FPROC(hv4, 4);  FPROC(hv5, 5);  FPROC(hv6, 6);   FPROC(hv7, 7);
  FPROC(hv8, 8);  FPROC(hv9, 9);  FPROC(hv10, 10); FPROC(hv11, 11);
  FPROC(hv12, 12); FPROC(hv13, 13); FPROC(hv14, 14); FPROC(hv15, 15);
#undef FPROC

  #pragma unroll
  for (int o = 0; o < 12; o++) out[(size_t)r*12 + o] = acc[o];
}

// ---------------- launch ----------------
extern "C" void kernel_launch(void* const* d_in, const int* in_sizes, int n_in,
                              void* d_out, int out_size, void* d_ws, size_t ws_size,
                              hipStream_t stream)
{
  const float* x   = (const float*)d_in[0];
  const float* W1  = (const float*)d_in[1];
  const float* b1  = (const float*)d_in[2];
  const float* g1  = (const float*)d_in[3];
  const float* be1 = (const float*)d_in[4];
  const float* W2  = (const float*)d_in[5];
  const float* b2  = (const float*)d_in[6];
  const float* g2  = (const float*)d_in[7];
  const float* be2 = (const float*)d_in[8];
  const float* W4  = (const float*)d_in[9];
  const float* b4  = (const float*)d_in[10];
  float* out = (float*)d_out;

  char* ws = (char*)d_ws;
  unsigned short* h1     = (unsigned short*)(ws);              //  8 MB  [16384,256] bf16
  unsigned short* h2     = (unsigned short*)(ws + 8388608);    //  4 MB  [16384,128] bf16
  unsigned short* w1s    = (unsigned short*)(ws + 12582912);   //  2 MB  [256,4096] bf16
  unsigned short* w2s    = (unsigned short*)(ws + 14680064);   // 64 KB  [128,256] bf16
  float*          part1s = (float*)(ws + 14745600);            // 256 KB [256][256]
  float*          part1q = (float*)(ws + 15007744);            // 256 KB
  float*          part2s = (float*)(ws + 15269888);            // 128 KB [128][256]
  float*          part2q = (float*)(ws + 15400960);            // 128 KB
  float*          ab1    = (float*)(ws + 15532032);            // a1[256], c1[256]
  float*          ab2    = (float*)(ws + 15534080);            // a2[128], c2[128]

  prep_sign_k<<<528, 256, 0, stream>>>(W1, w1s, W2, w2s);
  gemm1_k<<<256, 512, 0, stream>>>(x, w1s, b1, h1, part1s, part1q);
  params_k<256><<<1, 256, 0, stream>>>(part1s, part1q, g1, be1, ab1);
  gemm2_k<<<256, 512, 0, stream>>>(h1, w2s, b2, ab1, h2, part2s, part2q);
  params_k<128><<<1, 128, 0, stream>>>(part2s, part2q, g2, be2, ab2);
  final_k<<<256, 64, 0, stream>>>(h2, ab2, W4, b4, out);
}

// Round 4
// 125.954 us; speedup vs baseline: 1.3682x; 1.2455x over previous
//
#include <hip/hip_runtime.h>
#include <cstddef>

typedef __attribute__((ext_vector_type(8))) short short8;
typedef __attribute__((ext_vector_type(4))) float f4;
typedef __attribute__((ext_vector_type(4))) unsigned int u4;

__device__ __forceinline__ unsigned int f2bf(float f){
  unsigned int u = __float_as_uint(f);
  u += 0x7fffu + ((u >> 16) & 1u);   // RNE to bf16
  return u >> 16;
}
__device__ __forceinline__ float fsign(float x){ return (x > 0.f) ? 1.f : ((x < 0.f) ? -1.f : 0.f); }
__device__ __forceinline__ float hclip(float x){ return fminf(1.f, fmaxf(-1.f, x)); }

// Raw workgroup barrier: drain ONLY lgkm (LDS), never vmcnt — global prefetches
// stay in flight across the barrier (T4 counted-vmcnt discipline).
#define BARRIER() do { \
    __builtin_amdgcn_sched_barrier(0); \
    asm volatile("s_waitcnt lgkmcnt(0)" ::: "memory"); \
    __builtin_amdgcn_s_barrier(); \
    asm volatile("" ::: "memory"); \
    __builtin_amdgcn_sched_barrier(0); \
  } while(0)

// ---------------- prep: sign(W1)+sign(W2) fp32 -> bf16 {+1,-1,0}, one dispatch ----------------
__global__ void prep_sign_k(const float* __restrict__ W1, unsigned short* __restrict__ w1s,
                            const float* __restrict__ W2, unsigned short* __restrict__ w2s){
  int i = (blockIdx.x * blockDim.x + threadIdx.x) * 8;
  const float* w; unsigned short* o; int off;
  if (i < 1048576){ w = W1; o = w1s; off = i; }
  else            { w = W2; o = w2s; off = i - 1048576; if (off >= 32768) return; }
  f4 a = *(const f4*)(w + off);
  f4 b = *(const f4*)(w + off + 4);
  unsigned short s[8];
  #pragma unroll
  for (int j = 0; j < 4; j++) s[j]   = (a[j] > 0.f) ? 0x3F80u : ((a[j] < 0.f) ? 0xBF80u : 0u);
  #pragma unroll
  for (int j = 0; j < 4; j++) s[4+j] = (b[j] > 0.f) ? 0x3F80u : ((b[j] < 0.f) ? 0xBF80u : 0u);
  u4 v;
  v.x = (unsigned)s[0] | ((unsigned)s[1] << 16);
  v.y = (unsigned)s[2] | ((unsigned)s[3] << 16);
  v.z = (unsigned)s[4] | ((unsigned)s[5] << 16);
  v.w = (unsigned)s[6] | ((unsigned)s[7] << 16);
  *(u4*)(o + off) = v;
}

// ---------------- GEMM1: h1(bf16) = x @ signW1^T + sign(b1), fused transposed col-stats ----------
// BM=64, BN=256, BK=64, 512 thr = 8 waves, wave tile 64x32.
// A: depth-3 register prefetch -> LDS dbuf (XOR swizzle). B: depth-1 register prefetch from L2.
// Raw lgkm-only barriers: vmcnt never drains to 0 in the main loop.
__global__ __launch_bounds__(512) void gemm1_k(
    const float* __restrict__ x, const unsigned short* __restrict__ w1s,
    const float* __restrict__ b1, unsigned short* __restrict__ h1,
    float* __restrict__ part1s, float* __restrict__ part1q)
{
  __shared__ __align__(16) char lds[16384];
  const int tid  = threadIdx.x;
  const int lane = tid & 63;
  const int wid  = tid >> 6;          // 0..7 -> cols wid*32..+31
  const int cl   = lane & 15;
  const int g    = lane >> 4;         // 0..3
  const int klo  = g * 8;
  const int row0 = blockIdx.x * 64;

  // A staging: thread -> row am, 8 contiguous k at ak0
  const int am  = tid >> 3;
  const int ak0 = (tid & 7) * 8;
  const float* xA = x + (size_t)(row0 + am) * 4096 + ak0;
  const int aoff  = ((am * 128) + (ak0 * 2)) ^ ((am & 7) << 4);

  // B direct-load base: row n = wid*32 + cl (+16 for fn=1), k = klo (+32 for ks=1)
  const unsigned short* wbase = w1s + (size_t)(wid * 32 + cl) * 4096 + klo;

  f4 acc[4][2];
  const f4 z = {0.f, 0.f, 0.f, 0.f};
  #pragma unroll
  for (int i = 0; i < 4; i++){ acc[i][0] = z; acc[i][1] = z; }

  // A prefetch slots (depth 3, 4 rotating)
  f4 ra0a, ra0b, ra1a, ra1b, ra2a, ra2b, ra3a, ra3b;
  // B prefetch slots (depth 1, 2 alternating): 0=fn0ks0 1=fn0ks1 2=fn1ks0 3=fn1ks1
  short8 bq0, bq1, bq2, bq3, br0, br1, br2, br3;

#define LOADT(S, KB) do { \
    ra##S##a = *(const f4*)(xA + (KB)*64); \
    ra##S##b = *(const f4*)(xA + (KB)*64 + 4); \
  } while(0)

#define LOADB(P, KB) do { \
    b##P##0 = *(const short8*)(wbase + (KB)*64); \
    b##P##1 = *(const short8*)(wbase + (KB)*64 + 32); \
    b##P##2 = *(const short8*)(wbase + 65536 + (KB)*64); \
    b##P##3 = *(const short8*)(wbase + 65536 + (KB)*64 + 32); \
  } while(0)

#define WRITET(S, BUF) do { \
    u4 _va; \
    _va.x = f2bf(ra##S##a[0]) | (f2bf(ra##S##a[1]) << 16); \
    _va.y = f2bf(ra##S##a[2]) | (f2bf(ra##S##a[3]) << 16); \
    _va.z = f2bf(ra##S##b[0]) | (f2bf(ra##S##b[1]) << 16); \
    _va.w = f2bf(ra##S##b[2]) | (f2bf(ra##S##b[3]) << 16); \
    *(u4*)(lds + (BUF)*8192 + aoff) = _va; \
  } while(0)

#define COMPUTE(P, BUF) do { \
    const char* _ab = lds + (BUF)*8192; \
    short8 _af[4][2]; \
    _Pragma("unroll") \
    for (int fm = 0; fm < 4; fm++){ \
      int _m = fm*16 + cl; \
      _af[fm][0] = *(const short8*)(_ab + ((_m*128 + klo*2) ^ ((_m & 7) << 4))); \
      _af[fm][1] = *(const short8*)(_ab + ((_m*128 + (32 + klo)*2) ^ ((_m & 7) << 4))); \
    } \
    _Pragma("unroll") \
    for (int fm = 0; fm < 4; fm++){ \
      acc[fm][0] = __builtin_amdgcn_mfma_f32_16x16x32_bf16(_af[fm][0], b##P##0, acc[fm][0], 0, 0, 0); \
      acc[fm][1] = __builtin_amdgcn_mfma_f32_16x16x32_bf16(_af[fm][0], b##P##2, acc[fm][1], 0, 0, 0); \
      acc[fm][0] = __builtin_amdgcn_mfma_f32_16x16x32_bf16(_af[fm][1], b##P##1, acc[fm][0], 0, 0, 0); \
      acc[fm][1] = __builtin_amdgcn_mfma_f32_16x16x32_bf16(_af[fm][1], b##P##3, acc[fm][1], 0, 0, 0); \
    } \
  } while(0)

  LOADB(q, 0);
  LOADT(0, 0); LOADT(1, 1); LOADT(2, 2);
  WRITET(0, 0);
  BARRIER();
  for (int t = 0; t < 64; t += 4){
    // kb = t+0: use bq/buf0; prefetch br<-t+1, A slot3<-t+3; write slot1->buf1
    LOADB(r, t+1);
    COMPUTE(q, 0);
    __builtin_amdgcn_sched_barrier(0);
    LOADT(3, t+3);
    __builtin_amdgcn_sched_barrier(0);
    WRITET(1, 1);
    BARRIER();
    // kb = t+1: use br/buf1; prefetch bq<-t+2, A slot0<-t+4; write slot2->buf0
    LOADB(q, t+2);
    COMPUTE(r, 1);
    __builtin_amdgcn_sched_barrier(0);
    if (t+4 < 64) LOADT(0, t+4);
    __builtin_amdgcn_sched_barrier(0);
    WRITET(2, 0);
    BARRIER();
    // kb = t+2: use bq/buf0; prefetch br<-t+3, A slot1<-t+5; write slot3->buf1
    LOADB(r, t+3);
    COMPUTE(q, 0);
    __builtin_amdgcn_sched_barrier(0);
    if (t+5 < 64) LOADT(1, t+5);
    __builtin_amdgcn_sched_barrier(0);
    WRITET(3, 1);
    BARRIER();
    // kb = t+3: use br/buf1; prefetch bq<-t+4, A slot2<-t+6; write slot0->buf0
    if (t+4 < 64) LOADB(q, t+4);
    COMPUTE(r, 1);
    __builtin_amdgcn_sched_barrier(0);
    if (t+6 < 64) LOADT(2, t+6);
    __builtin_amdgcn_sched_barrier(0);
    if (t+4 < 64) WRITET(0, 0);
    BARRIER();
  }
#undef COMPUTE
#undef WRITET
#undef LOADB
#undef LOADT

  // epilogue: bf16 h1 write + fused transposed column stats
  #pragma unroll
  for (int fn = 0; fn < 2; fn++){
    int c = wid*32 + fn*16 + cl;
    float sb = fsign(b1[c]);
    float s = 0.f, q = 0.f;
    #pragma unroll
    for (int fm = 0; fm < 4; fm++){
      int rbase = row0 + fm*16 + g*4;
      #pragma unroll
      for (int i = 0; i < 4; i++){
        float v = acc[fm][fn][i] + sb;
        h1[(size_t)(rbase + i)*256 + c] = (unsigned short)f2bf(v);
        s += v; q += v*v;
      }
    }
    s += __shfl_xor(s, 16, 64); s += __shfl_xor(s, 32, 64);
    q += __shfl_xor(q, 16, 64); q += __shfl_xor(q, 32, 64);
    if (g == 0){
      part1s[c*256 + blockIdx.x] = s;
      part1q[c*256 + blockIdx.x] = q;
    }
  }
}

// ---------------- BN params from transposed partials (multi-block, 64 thr = 1 wave) -----------
// grid = COLS/64 blocks; col j = blockIdx*64 + tid; partials contiguous per col.
template<int COLS>
__global__ __launch_bounds__(64) void params_k(
    const float* __restrict__ ps, const float* __restrict__ pq,
    const float* __restrict__ g, const float* __restrict__ be,
    float* __restrict__ ab){
  int j = blockIdx.x * 64 + threadIdx.x;
  const f4* vs = (const f4*)(ps + j*256);
  const f4* vq = (const f4*)(pq + j*256);
  f4 s4 = {0,0,0,0}, q4 = {0,0,0,0};
  #pragma unroll 8
  for (int b = 0; b < 64; b++){ s4 += vs[b]; q4 += vq[b]; }
  float s = s4[0]+s4[1]+s4[2]+s4[3];
  float q = q4[0]+q4[1]+q4[2]+q4[3];
  float mu  = s * (1.f/16384.f);
  float var = q * (1.f/16384.f) - mu*mu;
  float a   = g[j] * rsqrtf(var + 1e-5f);
  ab[j] = a;
  ab[COLS + j] = be[j] - mu*a;
}

// ---------------- GEMM2: h2(bf16) = clip(BN1(h1)) @ signW2^T + sign(b2), fused stats -----------
// BM=64, BN=128, K=256 (4 steps), 512 thr = 8 waves, wave tile 64x16.
// A-only LDS dbuf, B direct from global (64KB, L2-hot). Raw lgkm-only barriers.
__global__ __launch_bounds__(512) void gemm2_k(
    const unsigned short* __restrict__ h1, const unsigned short* __restrict__ w2s,
    const float* __restrict__ b2, const float* __restrict__ ab1,
    unsigned short* __restrict__ h2, float* __restrict__ part2s, float* __restrict__ part2q)
{
  __shared__ __align__(16) char lds[16384];
  __shared__ __align__(16) float a1l[256];
  __shared__ __align__(16) float c1l[256];
  const int tid  = threadIdx.x;
  const int lane = tid & 63;
  const int wid  = tid >> 6;          // 0..7 -> cols wid*16..+15
  const int cl   = lane & 15;
  const int g    = lane >> 4;
  const int klo  = g * 8;
  const int row0 = blockIdx.x * 64;

  if (tid < 256) a1l[tid] = ab1[tid];
  else           c1l[tid - 256] = ab1[tid];

  const int am  = tid >> 3;
  const int ak0 = (tid & 7) * 8;
  const unsigned short* hA = h1 + (size_t)(row0 + am) * 256 + ak0;
  const int aw = ((am * 128) + (ak0 * 2)) ^ ((am & 7) << 4);

  const unsigned short* wbase = w2s + (size_t)(wid * 16 + cl) * 256 + klo;

  f4 acc[4];
  const f4 z = {0.f, 0.f, 0.f, 0.f};
  #pragma unroll
  for (int i = 0; i < 4; i++) acc[i] = z;

  auto writeA = [&](int buf, int kb, u4 raw){
    f4 a0 = *(const f4*)&a1l[kb*64 + ak0];
    f4 a1 = *(const f4*)&a1l[kb*64 + ak0 + 4];
    f4 c0 = *(const f4*)&c1l[kb*64 + ak0];
    f4 c1 = *(const f4*)&c1l[kb*64 + ak0 + 4];
    float t0 = hclip(a0[0]*__uint_as_float((raw.x & 0xFFFFu) << 16) + c0[0]);
    float t1 = hclip(a0[1]*__uint_as_float( raw.x & 0xFFFF0000u   ) + c0[1]);
    float t2 = hclip(a0[2]*__uint_as_float((raw.y & 0xFFFFu) << 16) + c0[2]);
    float t3 = hclip(a0[3]*__uint_as_float( raw.y & 0xFFFF0000u   ) + c0[3]);
    float t4 = hclip(a1[0]*__uint_as_float((raw.z & 0xFFFFu) << 16) + c1[0]);
    float t5 = hclip(a1[1]*__uint_as_float( raw.z & 0xFFFF0000u   ) + c1[1]);
    float t6 = hclip(a1[2]*__uint_as_float((raw.w & 0xFFFFu) << 16) + c1[2]);
    float t7 = hclip(a1[3]*__uint_as_float( raw.w & 0xFFFF0000u   ) + c1[3]);
    u4 v;
    v.x = f2bf(t0) | (f2bf(t1) << 16);
    v.y = f2bf(t2) | (f2bf(t3) << 16);
    v.z = f2bf(t4) | (f2bf(t5) << 16);
    v.w = f2bf(t6) | (f2bf(t7) << 16);
    *(u4*)(lds + buf*8192 + aw) = v;
  };
  auto compute = [&](int buf, int kb){
    short8 bf[2];
    #pragma unroll
    for (int ks = 0; ks < 2; ks++)
      bf[ks] = *(const short8*)(wbase + kb*64 + ks*32);
    const char* abuf = lds + buf*8192;
    short8 af[4][2];
    #pragma unroll
    for (int fm = 0; fm < 4; fm++){
      int m = fm*16 + cl;
      #pragma unroll
      for (int ks = 0; ks < 2; ks++){
        int off = (m*128 + (ks*32 + klo)*2) ^ ((m & 7) << 4);
        af[fm][ks] = *(const short8*)(abuf + off);
      }
    }
    #pragma unroll
    for (int ks = 0; ks < 2; ks++)
      #pragma unroll
      for (int fm = 0; fm < 4; fm++)
        acc[fm] = __builtin_amdgcn_mfma_f32_16x16x32_bf16(af[fm][ks], bf[ks], acc[fm], 0, 0, 0);
  };

  u4 raw0 = *(const u4*)(hA);
  BARRIER();                 // a1l/c1l visible
  writeA(0, 0, raw0);
  BARRIER();
  #pragma unroll
  for (int kb = 0; kb < 4; kb++){
    u4 rawn;
    if (kb < 3) rawn = *(const u4*)(hA + (kb+1)*64);
    compute(kb & 1, kb);
    if (kb < 3) writeA((kb+1) & 1, kb+1, rawn);
    BARRIER();
  }

  {
    int c = wid*16 + cl;
    float sb = fsign(b2[c]);
    float s = 0.f, q = 0.f;
    #pragma unroll
    for (int fm = 0; fm < 4; fm++){
      int rbase = row0 + fm*16 + g*4;
      #pragma unroll
      for (int i = 0; i < 4; i++){
        float v = acc[fm][i] + sb;
        h2[(size_t)(rbase + i)*128 + c] = (unsigned short)f2bf(v);
        s += v; q += v*v;
      }
    }
    s += __shfl_xor(s, 16, 64); s += __shfl_xor(s, 32, 64);
    q += __shfl_xor(q, 16, 64); q += __shfl_xor(q, 32, 64);
    if (g == 0){
      part2s[c*256 + blockIdx.x] = s;
      part2q[c*256 + blockIdx.x] = q;
    }
  }
}

// ---------------- final: out = clip(BN2(h2)) @ W4^T + b4  (fp32 VALU, N=12) --------------------
__global__ __launch_bounds__(64) void final_k(
    const unsigned short* __restrict__ h2, const float* __restrict__ ab2,
    const float* __restrict__ W4, const float* __restrict__ b4,
    float* __restrict__ out)
{
  __shared__ __align__(16) float W4l[12*128];
  __shared__ __align__(16) float a2l[128];
  __shared__ __align__(16) float c2l[128];
  const int t = threadIdx.x;
  #pragma unroll
  for (int i = 0; i < 6; i++)
    *(f4*)&W4l[(i*64 + t)*4] = *(const f4*)(W4 + (i*64 + t)*4);
  a2l[t]      = ab2[t];
  a2l[t + 64] = ab2[t + 64];
  c2l[t]      = ab2[128 + t];
  c2l[t + 64] = ab2[192 + t];
  __syncthreads();

  const int r = blockIdx.x * 64 + t;
  const u4* hp = (const u4*)(h2 + (size_t)r * 128);
  u4 hv0 = hp[0], hv1 = hp[1], hv2 = hp[2],  hv3 = hp[3];
  u4 hv4 = hp[4], hv5 = hp[5], hv6 = hp[6],  hv7 = hp[7];
  u4 hv8 = hp[8], hv9 = hp[9], hv10 = hp[10], hv11 = hp[11];
  u4 hv12 = hp[12], hv13 = hp[13], hv14 = hp[14], hv15 = hp[15];

  float acc[12];
  #pragma unroll
  for (int o = 0; o < 12; o++) acc[o] = b4[o];

#define FPROC(HV, J) do { \
    f4 a0 = *(const f4*)&a2l[(J)*8];     f4 a1 = *(const f4*)&a2l[(J)*8 + 4]; \
    f4 c0 = *(const f4*)&c2l[(J)*8];     f4 c1 = *(const f4*)&c2l[(J)*8 + 4]; \
    float tt0 = hclip(a0[0]*__uint_as_float((HV.x & 0xFFFFu) << 16) + c0[0]); \
    float tt1 = hclip(a0[1]*__uint_as_float( HV.x & 0xFFFF0000u   ) + c0[1]); \
    float tt2 = hclip(a0[2]*__uint_as_float((HV.y & 0xFFFFu) << 16) + c0[2]); \
    float tt3 = hclip(a0[3]*__uint_as_float( HV.y & 0xFFFF0000u   ) + c0[3]); \
    float tt4 = hclip(a1[0]*__uint_as_float((HV.z & 0xFFFFu) << 16) + c1[0]); \
    float tt5 = hclip(a1[1]*__uint_as_float( HV.z & 0xFFFF0000u   ) + c1[1]); \
    float tt6 = hclip(a1[2]*__uint_as_float((HV.w & 0xFFFFu) << 16) + c1[2]); \
    float tt7 = hclip(a1[3]*__uint_as_float( HV.w & 0xFFFF0000u   ) + c1[3]); \
    _Pragma("unroll") \
    for (int o = 0; o < 12; o++){ \
      f4 w0 = *(const f4*)&W4l[o*128 + (J)*8]; \
      f4 w1 = *(const f4*)&W4l[o*128 + (J)*8 + 4]; \
      acc[o] += tt0*w0[0] + tt1*w0[1] + tt2*w0[2] + tt3*w0[3] \
              + tt4*w1[0] + tt5*w1[1] + tt6*w1[2] + tt7*w1[3]; \
    } \
  } while(0)

  FPROC(hv0, 0);  FPROC(hv1, 1);  FPROC(hv2, 2);   FPROC(hv3, 3);
  FPROC(hv4, 4);  FPROC(hv5, 5);  FPROC(hv6, 6);   FPROC(hv7, 7);
  FPROC(hv8, 8);  FPROC(hv9, 9);  FPROC(hv10, 10); FPROC(hv11, 11);
  FPROC(hv12, 12); FPROC(hv13, 13); FPROC(hv14, 14); FPROC(hv15, 15);
#undef FPROC

  #pragma unroll
  for (int o = 0; o < 12; o++) out[(size_t)r*12 + o] = acc[o];
}

// ---------------- launch ----------------
extern "C" void kernel_launch(void* const* d_in, const int* in_sizes, int n_in,
                              void* d_out, int out_size, void* d_ws, size_t ws_size,
                              hipStream_t stream)
{
  const float* x   = (const float*)d_in[0];
  const float* W1  = (const float*)d_in[1];
  const float* b1  = (const float*)d_in[2];
  const float* g1  = (const float*)d_in[3];
  const float* be1 = (const float*)d_in[4];
  const float* W2  = (const float*)d_in[5];
  const float* b2  = (const float*)d_in[6];
  const float* g2  = (const float*)d_in[7];
  const float* be2 = (const float*)d_in[8];
  const float* W4  = (const float*)d_in[9];
  const float* b4  = (const float*)d_in[10];
  float* out = (float*)d_out;

  char* ws = (char*)d_ws;
  unsigned short* h1     = (unsigned short*)(ws);              //  8 MB  [16384,256] bf16
  unsigned short* h2     = (unsigned short*)(ws + 8388608);    //  4 MB  [16384,128] bf16
  unsigned short* w1s    = (unsigned short*)(ws + 12582912);   //  2 MB  [256,4096] bf16
  unsigned short* w2s    = (unsigned short*)(ws + 14680064);   // 64 KB  [128,256] bf16
  float*          part1s = (float*)(ws + 14745600);            // 256 KB [256][256]
  float*          part1q = (float*)(ws + 15007744);            // 256 KB
  float*          part2s = (float*)(ws + 15269888);            // 128 KB [128][256]
  float*          part2q = (float*)(ws + 15400960);            // 128 KB
  float*          ab1    = (float*)(ws + 15532032);            // a1[256], c1[256]
  float*          ab2    = (float*)(ws + 15534080);            // a2[128], c2[128]

  prep_sign_k<<<528, 256, 0, stream>>>(W1, w1s, W2, w2s);
  gemm1_k<<<256, 512, 0, stream>>>(x, w1s, b1, h1, part1s, part1q);
  params_k<256><<<4, 64, 0, stream>>>(part1s, part1q, g1, be1, ab1);
  gemm2_k<<<256, 512, 0, stream>>>(h1, w2s, b2, ab1, h2, part2s, part2q);
  params_k<128><<<2, 64, 0, stream>>>(part2s, part2q, g2, be2, ab2);
  final_k<<<256, 64, 0, stream>>>(h2, ab2, W4, b4, out);
}

// Round 5
// 125.476 us; speedup vs baseline: 1.3734x; 1.0038x over previous
//
#include <hip/hip_runtime.h>
#include <cstddef>

typedef __attribute__((ext_vector_type(8))) short short8;
typedef __attribute__((ext_vector_type(4))) float f4;
typedef __attribute__((ext_vector_type(4))) unsigned int u4;

__device__ __forceinline__ unsigned int f2bf(float f){
  unsigned int u = __float_as_uint(f);
  u += 0x7fffu + ((u >> 16) & 1u);   // RNE to bf16
  return u >> 16;
}
__device__ __forceinline__ float bflo(unsigned int w){ return __uint_as_float((w & 0xFFFFu) << 16); }
__device__ __forceinline__ float bfhi(unsigned int w){ return __uint_as_float(w & 0xFFFF0000u); }
__device__ __forceinline__ float fsign(float x){ return (x > 0.f) ? 1.f : ((x < 0.f) ? -1.f : 0.f); }
__device__ __forceinline__ float hclip(float x){ return fminf(1.f, fmaxf(-1.f, x)); }

// Raw workgroup barrier: drain ONLY lgkm (LDS) — global loads stay in flight.
#define BARRIER() do { \
    __builtin_amdgcn_sched_barrier(0); \
    asm volatile("s_waitcnt lgkmcnt(0)" ::: "memory"); \
    __builtin_amdgcn_s_barrier(); \
    asm volatile("" ::: "memory"); \
    __builtin_amdgcn_sched_barrier(0); \
  } while(0)

// ---------------- prep: sign(W1)+sign(W2) fp32 -> bf16 {+1,-1,0}, one dispatch ----------------
__global__ void prep_sign_k(const float* __restrict__ W1, unsigned short* __restrict__ w1s,
                            const float* __restrict__ W2, unsigned short* __restrict__ w2s){
  int i = (blockIdx.x * blockDim.x + threadIdx.x) * 8;
  const float* w; unsigned short* o; int off;
  if (i < 1048576){ w = W1; o = w1s; off = i; }
  else            { w = W2; o = w2s; off = i - 1048576; if (off >= 32768) return; }
  f4 a = *(const f4*)(w + off);
  f4 b = *(const f4*)(w + off + 4);
  unsigned short s[8];
  #pragma unroll
  for (int j = 0; j < 4; j++) s[j]   = (a[j] > 0.f) ? 0x3F80u : ((a[j] < 0.f) ? 0xBF80u : 0u);
  #pragma unroll
  for (int j = 0; j < 4; j++) s[4+j] = (b[j] > 0.f) ? 0x3F80u : ((b[j] < 0.f) ? 0xBF80u : 0u);
  u4 v;
  v.x = (unsigned)s[0] | ((unsigned)s[1] << 16);
  v.y = (unsigned)s[2] | ((unsigned)s[3] << 16);
  v.z = (unsigned)s[4] | ((unsigned)s[5] << 16);
  v.w = (unsigned)s[6] | ((unsigned)s[7] << 16);
  *(u4*)(o + off) = v;
}

// ---------------- GEMM1: h1(bf16) = x @ signW1^T + sign(b1), fused transposed col-stats ---------
// BM=64, BN=256, 512 thr = 8 waves, wave tile 64x32. 4 K-steps (BK=64 each) per barrier phase:
// 8 x 8KB LDS buffers (two 4-buffer halves, swap per phase). Phase p issues ALL A-loads for
// phase p+1 at its top (issue->use = one full phase >> HBM latency), computes 4 substeps with
// B depth-1 register prefetch from L2, packs+writes 4 buffers, one lgkm-only barrier. 16 barriers.
__global__ __launch_bounds__(512) void gemm1_k(
    const float* __restrict__ x, const unsigned short* __restrict__ w1s,
    const float* __restrict__ b1, unsigned short* __restrict__ h1,
    float* __restrict__ part1s, float* __restrict__ part1q)
{
  __shared__ __align__(16) char lds[65536];
  const int tid  = threadIdx.x;
  const int lane = tid & 63;
  const int wid  = tid >> 6;          // 0..7 -> cols wid*32..+31
  const int cl   = lane & 15;
  const int g    = lane >> 4;         // 0..3
  const int klo  = g * 8;
  const int row0 = blockIdx.x * 64;

  // A staging: thread -> row am, 8 contiguous k at ak0
  const int am  = tid >> 3;
  const int ak0 = (tid & 7) * 8;
  const float* xA = x + (size_t)(row0 + am) * 4096 + ak0;
  const int aoff  = ((am * 128) + (ak0 * 2)) ^ ((am & 7) << 4);

  // B direct-load base: row n = wid*32 + cl (+16 for fn=1), k = klo (+32 for ks=1)
  const unsigned short* wbase = w1s + (size_t)(wid * 32 + cl) * 4096 + klo;

  f4 acc[4][2];
  const f4 z = {0.f, 0.f, 0.f, 0.f};
  #pragma unroll
  for (int i = 0; i < 4; i++){ acc[i][0] = z; acc[i][1] = z; }

  // A staging regs: one phase's worth (4 substeps x 32B)
  f4 rA0a, rA0b, rA1a, rA1b, rA2a, rA2b, rA3a, rA3b;
  // B slots (depth-1): q/r x {fn0ks0, fn0ks1, fn1ks0, fn1ks1}
  short8 Bq0, Bq1, Bq2, Bq3, Br0, Br1, Br2, Br3;

#define LOADA4(KB0) do { \
    rA0a = *(const f4*)(xA + (KB0+0)*64); rA0b = *(const f4*)(xA + (KB0+0)*64 + 4); \
    rA1a = *(const f4*)(xA + (KB0+1)*64); rA1b = *(const f4*)(xA + (KB0+1)*64 + 4); \
    rA2a = *(const f4*)(xA + (KB0+2)*64); rA2b = *(const f4*)(xA + (KB0+2)*64 + 4); \
    rA3a = *(const f4*)(xA + (KB0+3)*64); rA3b = *(const f4*)(xA + (KB0+3)*64 + 4); \
  } while(0)

#define PACK1(DST, RA, RB) do { \
    u4 _v; \
    _v.x = f2bf(RA[0]) | (f2bf(RA[1]) << 16); \
    _v.y = f2bf(RA[2]) | (f2bf(RA[3]) << 16); \
    _v.z = f2bf(RB[0]) | (f2bf(RB[1]) << 16); \
    _v.w = f2bf(RB[2]) | (f2bf(RB[3]) << 16); \
    *(u4*)(DST) = _v; \
  } while(0)

#define WRITEA4(WB) do { \
    PACK1((WB) +     0 + aoff, rA0a, rA0b); \
    PACK1((WB) +  8192 + aoff, rA1a, rA1b); \
    PACK1((WB) + 16384 + aoff, rA2a, rA2b); \
    PACK1((WB) + 24576 + aoff, rA3a, rA3b); \
  } while(0)

#define LOADB(P, KB) do { \
    B##P##0 = *(const short8*)(wbase + (KB)*64); \
    B##P##1 = *(const short8*)(wbase + (KB)*64 + 32); \
    B##P##2 = *(const short8*)(wbase + 65536 + (KB)*64); \
    B##P##3 = *(const short8*)(wbase + 65536 + (KB)*64 + 32); \
  } while(0)

#define COMPUTE(BASE, P) do { \
    const char* _ab = (const char*)(BASE); \
    short8 _af[4][2]; \
    _Pragma("unroll") \
    for (int fm = 0; fm < 4; fm++){ \
      int _m = fm*16 + cl; \
      _af[fm][0] = *(const short8*)(_ab + ((_m*128 + klo*2) ^ ((_m & 7) << 4))); \
      _af[fm][1] = *(const short8*)(_ab + ((_m*128 + (32 + klo)*2) ^ ((_m & 7) << 4))); \
    } \
    _Pragma("unroll") \
    for (int fm = 0; fm < 4; fm++){ \
      acc[fm][0] = __builtin_amdgcn_mfma_f32_16x16x32_bf16(_af[fm][0], B##P##0, acc[fm][0], 0, 0, 0); \
      acc[fm][1] = __builtin_amdgcn_mfma_f32_16x16x32_bf16(_af[fm][0], B##P##2, acc[fm][1], 0, 0, 0); \
      acc[fm][0] = __builtin_amdgcn_mfma_f32_16x16x32_bf16(_af[fm][1], B##P##1, acc[fm][0], 0, 0, 0); \
      acc[fm][1] = __builtin_amdgcn_mfma_f32_16x16x32_bf16(_af[fm][1], B##P##3, acc[fm][1], 0, 0, 0); \
    } \
  } while(0)

  // prologue: stage phase 0's buffers, first B
  LOADA4(0);
  WRITEA4(lds);
  LOADB(q, 0);
  BARRIER();

  for (int p = 0; p < 16; ++p){
    const bool pg = (p < 15);
    char* rbuf = lds + ((p & 1) << 15);
    char* wbuf = lds + (((p & 1) ^ 1) << 15);
    if (pg) LOADA4(4*p + 4);          // issue next phase's A early (oldest VMEM)
    __builtin_amdgcn_sched_barrier(0);
    LOADB(r, 4*p + 1);
    COMPUTE(rbuf,         q);
    LOADB(q, 4*p + 2);
    COMPUTE(rbuf +  8192, r);
    LOADB(r, 4*p + 3);
    COMPUTE(rbuf + 16384, q);
    if (pg) LOADB(q, 4*p + 4);
    COMPUTE(rbuf + 24576, r);
    __builtin_amdgcn_sched_barrier(0);
    if (pg) WRITEA4(wbuf);            // counted vmcnt wait on this phase's A-loads only
    BARRIER();
  }
#undef COMPUTE
#undef LOADB
#undef WRITEA4
#undef PACK1
#undef LOADA4

  // epilogue: bf16 h1 write + fused transposed column stats
  #pragma unroll
  for (int fn = 0; fn < 2; fn++){
    int c = wid*32 + fn*16 + cl;
    float sb = fsign(b1[c]);
    float s = 0.f, q = 0.f;
    #pragma unroll
    for (int fm = 0; fm < 4; fm++){
      int rbase = row0 + fm*16 + g*4;
      #pragma unroll
      for (int i = 0; i < 4; i++){
        float v = acc[fm][fn][i] + sb;
        h1[(size_t)(rbase + i)*256 + c] = (unsigned short)f2bf(v);
        s += v; q += v*v;
      }
    }
    s += __shfl_xor(s, 16, 64); s += __shfl_xor(s, 32, 64);
    q += __shfl_xor(q, 16, 64); q += __shfl_xor(q, 32, 64);
    if (g == 0){
      part1s[c*256 + blockIdx.x] = s;
      part1q[c*256 + blockIdx.x] = q;
    }
  }
}

// ---------------- BN params from transposed partials (multi-block, 64 thr = 1 wave) -----------
template<int COLS>
__global__ __launch_bounds__(64) void params_k(
    const float* __restrict__ ps, const float* __restrict__ pq,
    const float* __restrict__ g, const float* __restrict__ be,
    float* __restrict__ ab){
  int j = blockIdx.x * 64 + threadIdx.x;
  const f4* vs = (const f4*)(ps + j*256);
  const f4* vq = (const f4*)(pq + j*256);
  f4 s4 = {0,0,0,0}, q4 = {0,0,0,0};
  #pragma unroll 8
  for (int b = 0; b < 64; b++){ s4 += vs[b]; q4 += vq[b]; }
  float s = s4[0]+s4[1]+s4[2]+s4[3];
  float q = q4[0]+q4[1]+q4[2]+q4[3];
  float mu  = s * (1.f/16384.f);
  float var = q * (1.f/16384.f) - mu*mu;
  float a   = g[j] * rsqrtf(var + 1e-5f);
  ab[j] = a;
  ab[COLS + j] = be[j] - mu*a;
}

// ---------------- GEMM2: h2(bf16) = clip(BN1(h1)) @ signW2^T + sign(b2), fused stats -----------
// BM=64, BN=128, K=256, 512 thr = 8 waves, wave tile 64x16. Whole A-tile (32KB) staged at once,
// BN params read per-thread from global (L2-hot), SINGLE barrier, then 4 read-only substeps.
__global__ __launch_bounds__(512) void gemm2_k(
    const unsigned short* __restrict__ h1, const unsigned short* __restrict__ w2s,
    const float* __restrict__ b2, const float* __restrict__ ab1,
    unsigned short* __restrict__ h2, float* __restrict__ part2s, float* __restrict__ part2q)
{
  __shared__ __align__(16) char lds[32768];
  const int tid  = threadIdx.x;
  const int lane = tid & 63;
  const int wid  = tid >> 6;          // 0..7 -> cols wid*16..+15
  const int cl   = lane & 15;
  const int g    = lane >> 4;
  const int klo  = g * 8;
  const int row0 = blockIdx.x * 64;

  const int am  = tid >> 3;
  const int ak0 = (tid & 7) * 8;
  const unsigned short* hA = h1 + (size_t)(row0 + am) * 256 + ak0;
  const int aw = ((am * 128) + (ak0 * 2)) ^ ((am & 7) << 4);
  const unsigned short* wbase = w2s + (size_t)(wid * 16 + cl) * 256 + klo;

  // issue everything up front
  u4 q0 = *(const u4*)(hA);
  u4 q1 = *(const u4*)(hA + 64);
  u4 q2 = *(const u4*)(hA + 128);
  u4 q3 = *(const u4*)(hA + 192);
  short8 Bq0, Bq1, Br0, Br1;
  Bq0 = *(const short8*)(wbase);
  Bq1 = *(const short8*)(wbase + 32);

#define TRW(KB, RAW) do { \
    f4 _a0 = *(const f4*)(ab1 + (KB)*64 + ak0); \
    f4 _a1 = *(const f4*)(ab1 + (KB)*64 + ak0 + 4); \
    f4 _c0 = *(const f4*)(ab1 + 256 + (KB)*64 + ak0); \
    f4 _c1 = *(const f4*)(ab1 + 256 + (KB)*64 + ak0 + 4); \
    float _t0 = hclip(_a0[0]*bflo(RAW.x) + _c0[0]); \
    float _t1 = hclip(_a0[1]*bfhi(RAW.x) + _c0[1]); \
    float _t2 = hclip(_a0[2]*bflo(RAW.y) + _c0[2]); \
    float _t3 = hclip(_a0[3]*bfhi(RAW.y) + _c0[3]); \
    float _t4 = hclip(_a1[0]*bflo(RAW.z) + _c1[0]); \
    float _t5 = hclip(_a1[1]*bfhi(RAW.z) + _c1[1]); \
    float _t6 = hclip(_a1[2]*bflo(RAW.w) + _c1[2]); \
    float _t7 = hclip(_a1[3]*bfhi(RAW.w) + _c1[3]); \
    u4 _v; \
    _v.x = f2bf(_t0) | (f2bf(_t1) << 16); \
    _v.y = f2bf(_t2) | (f2bf(_t3) << 16); \
    _v.z = f2bf(_t4) | (f2bf(_t5) << 16); \
    _v.w = f2bf(_t6) | (f2bf(_t7) << 16); \
    *(u4*)(lds + (KB)*8192 + aw) = _v; \
  } while(0)

  TRW(0, q0); TRW(1, q1); TRW(2, q2); TRW(3, q3);
#undef TRW
  BARRIER();   // the only barrier

  f4 acc[4];
  const f4 z = {0.f, 0.f, 0.f, 0.f};
  #pragma unroll
  for (int i = 0; i < 4; i++) acc[i] = z;

#define LOADB2(P, KB) do { \
    B##P##0 = *(const short8*)(wbase + (KB)*64); \
    B##P##1 = *(const short8*)(wbase + (KB)*64 + 32); \
  } while(0)

#define COMP2(BASE, P) do { \
    const char* _ab = (const char*)(BASE); \
    short8 _af[4][2]; \
    _Pragma("unroll") \
    for (int fm = 0; fm < 4; fm++){ \
      int _m = fm*16 + cl; \
      _af[fm][0] = *(const short8*)(_ab + ((_m*128 + klo*2) ^ ((_m & 7) << 4))); \
      _af[fm][1] = *(const short8*)(_ab + ((_m*128 + (32 + klo)*2) ^ ((_m & 7) << 4))); \
    } \
    _Pragma("unroll") \
    for (int fm = 0; fm < 4; fm++){ \
      acc[fm] = __builtin_amdgcn_mfma_f32_16x16x32_bf16(_af[fm][0], B##P##0, acc[fm], 0, 0, 0); \
      acc[fm] = __builtin_amdgcn_mfma_f32_16x16x32_bf16(_af[fm][1], B##P##1, acc[fm], 0, 0, 0); \
    } \
  } while(0)

  LOADB2(r, 1);
  COMP2(lds,         q);
  LOADB2(q, 2);
  COMP2(lds +  8192, r);
  LOADB2(r, 3);
  COMP2(lds + 16384, q);
  COMP2(lds + 24576, r);
#undef COMP2
#undef LOADB2

  {
    int c = wid*16 + cl;
    float sb = fsign(b2[c]);
    float s = 0.f, q = 0.f;
    #pragma unroll
    for (int fm = 0; fm < 4; fm++){
      int rbase = row0 + fm*16 + g*4;
      #pragma unroll
      for (int i = 0; i < 4; i++){
        float v = acc[fm][i] + sb;
        h2[(size_t)(rbase + i)*128 + c] = (unsigned short)f2bf(v);
        s += v; q += v*v;
      }
    }
    s += __shfl_xor(s, 16, 64); s += __shfl_xor(s, 32, 64);
    q += __shfl_xor(q, 16, 64); q += __shfl_xor(q, 32, 64);
    if (g == 0){
      part2s[c*256 + blockIdx.x] = s;
      part2q[c*256 + blockIdx.x] = q;
    }
  }
}

// ---------------- final: out = clip(BN2(h2)) @ W4^T + b4  (fp32 VALU, N=12) --------------------
__global__ __launch_bounds__(64) void final_k(
    const unsigned short* __restrict__ h2, const float* __restrict__ ab2,
    const float* __restrict__ W4, const float* __restrict__ b4,
    float* __restrict__ out)
{
  __shared__ __align__(16) float W4l[12*128];
  __shared__ __align__(16) float a2l[128];
  __shared__ __align__(16) float c2l[128];
  const int t = threadIdx.x;
  #pragma unroll
  for (int i = 0; i < 6; i++)
    *(f4*)&W4l[(i*64 + t)*4] = *(const f4*)(W4 + (i*64 + t)*4);
  a2l[t]      = ab2[t];
  a2l[t + 64] = ab2[t + 64];
  c2l[t]      = ab2[128 + t];
  c2l[t + 64] = ab2[192 + t];
  __syncthreads();

  const int r = blockIdx.x * 64 + t;
  const u4* hp = (const u4*)(h2 + (size_t)r * 128);
  u4 hv0 = hp[0], hv1 = hp[1], hv2 = hp[2],  hv3 = hp[3];
  u4 hv4 = hp[4], hv5 = hp[5], hv6 = hp[6],  hv7 = hp[7];
  u4 hv8 = hp[8], hv9 = hp[9], hv10 = hp[10], hv11 = hp[11];
  u4 hv12 = hp[12], hv13 = hp[13], hv14 = hp[14], hv15 = hp[15];

  float acc[12];
  #pragma unroll
  for (int o = 0; o < 12; o++) acc[o] = b4[o];

#define FPROC(HV, J) do { \
    f4 a0 = *(const f4*)&a2l[(J)*8];     f4 a1 = *(const f4*)&a2l[(J)*8 + 4]; \
    f4 c0 = *(const f4*)&c2l[(J)*8];     f4 c1 = *(const f4*)&c2l[(J)*8 + 4]; \
    float tt0 = hclip(a0[0]*bflo(HV.x) + c0[0]); \
    float tt1 = hclip(a0[1]*bfhi(HV.x) + c0[1]); \
    float tt2 = hclip(a0[2]*bflo(HV.y) + c0[2]); \
    float tt3 = hclip(a0[3]*bfhi(HV.y) + c0[3]); \
    float tt4 = hclip(a1[0]*bflo(HV.z) + c1[0]); \
    float tt5 = hclip(a1[1]*bfhi(HV.z) + c1[1]); \
    float tt6 = hclip(a1[2]*bflo(HV.w) + c1[2]); \
    float tt7 = hclip(a1[3]*bfhi(HV.w) + c1[3]); \
    _Pragma("unroll") \
    for (int o = 0; o < 12; o++){ \
      f4 w0 = *(const f4*)&W4l[o*128 + (J)*8]; \
      f4 w1 = *(const f4*)&W4l[o*128 + (J)*8 + 4]; \
      acc[o] += tt0*w0[0] + tt1*w0[1] + tt2*w0[2] + tt3*w0[3] \
              + tt4*w1[0] + tt5*w1[1] + tt6*w1[2] + tt7*w1[3]; \
    } \
  } while(0)

  FPROC(hv0, 0);  FPROC(hv1, 1);  FPROC(hv2, 2);   FPROC(hv3, 3);
  FPROC(hv4, 4);  FPROC(hv5, 5);  FPROC(hv6, 6);   FPROC(hv7, 7);
  FPROC(hv8, 8);  FPROC(hv9, 9);  FPROC(hv10, 10); FPROC(hv11, 11);
  FPROC(hv12, 12); FPROC(hv13, 13); FPROC(hv14, 14); FPROC(hv15, 15);
#undef FPROC

  #pragma unroll
  for (int o = 0; o < 12; o++) out[(size_t)r*12 + o] = acc[o];
}

// ---------------- launch ----------------
extern "C" void kernel_launch(void* const* d_in, const int* in_sizes, int n_in,
                              void* d_out, int out_size, void* d_ws, size_t ws_size,
                              hipStream_t stream)
{
  const float* x   = (const float*)d_in[0];
  const float* W1  = (const float*)d_in[1];
  const float* b1  = (const float*)d_in[2];
  const float* g1  = (const float*)d_in[3];
  const float* be1 = (const float*)d_in[4];
  const float* W2  = (const float*)d_in[5];
  const float* b2  = (const float*)d_in[6];
  const float* g2  = (const float*)d_in[7];
  const float* be2 = (const float*)d_in[8];
  const float* W4  = (const float*)d_in[9];
  const float* b4  = (const float*)d_in[10];
  float* out = (float*)d_out;

  char* ws = (char*)d_ws;
  unsigned short* h1     = (unsigned short*)(ws);              //  8 MB  [16384,256] bf16
  unsigned short* h2     = (unsigned short*)(ws + 8388608);    //  4 MB  [16384,128] bf16
  unsigned short* w1s    = (unsigned short*)(ws + 12582912);   //  2 MB  [256,4096] bf16
  unsigned short* w2s    = (unsigned short*)(ws + 14680064);   // 64 KB  [128,256] bf16
  float*          part1s = (float*)(ws + 14745600);            // 256 KB [256][256]
  float*          part1q = (float*)(ws + 15007744);            // 256 KB
  float*          part2s = (float*)(ws + 15269888);            // 128 KB [128][256]
  float*          part2q = (float*)(ws + 15400960);            // 128 KB
  float*          ab1    = (float*)(ws + 15532032);            // a1[256], c1[256]
  float*          ab2    = (float*)(ws + 15534080);            // a2[128], c2[128]

  prep_sign_k<<<528, 256, 0, stream>>>(W1, w1s, W2, w2s);
  gemm1_k<<<256, 512, 0, stream>>>(x, w1s, b1, h1, part1s, part1q);
  params_k<256><<<4, 64, 0, stream>>>(part1s, part1q, g1, be1, ab1);
  gemm2_k<<<256, 512, 0, stream>>>(h1, w2s, b2, ab1, h2, part2s, part2q);
  params_k<128><<<2, 64, 0, stream>>>(part2s, part2q, g2, be2, ab2);
  final_k<<<256, 64, 0, stream>>>(h2, ab2, W4, b4, out);
}